// Round 11
// baseline (447.369 us; speedup 1.0000x reference)
//
#include <hip/hip_runtime.h>
#include <math.h>

#define L_SEQ 1024
#define NB 4
#define NH 16
#define DH 64
#define BH_TOT (NB * NH)            // 64
#define GQ_TOT (BH_TOT * L_SEQ)     // 65536
#define NPOS 257                    // 2*128+1
#define QP_STRIDE 260               // padded Qp row stride (u16 elements)
#define LDK 72                      // LDS K-stride (bf16) for attn/gemm tiles
#define LDQP 72                     // stride for QpsP (u16; mult of 8 -> 16B-aligned b128)
#define LDPV 264                    // pvT row stride (u16)

typedef unsigned short ushort_t;
typedef __attribute__((ext_vector_type(8))) short bf16x8;
typedef __attribute__((ext_vector_type(4))) float f32x4;

__device__ inline ushort_t f2bf_rne(float x) {
    unsigned u = __float_as_uint(x);
    unsigned r = u + 0x7FFFu + ((u >> 16) & 1u);
    return (ushort_t)(r >> 16);
}
__device__ inline float bf2f(ushort_t h) {
    return __uint_as_float(((unsigned)h) << 16);
}
__device__ inline void split8(float4 a0, float4 a1, uint4* H, uint4* L) {
    float v[8] = {a0.x, a0.y, a0.z, a0.w, a1.x, a1.y, a1.z, a1.w};
    unsigned hh[4], ll[4];
    #pragma unroll
    for (int j = 0; j < 4; j++) {
        ushort_t h0 = f2bf_rne(v[2*j]),   h1 = f2bf_rne(v[2*j+1]);
        ushort_t l0 = f2bf_rne(v[2*j]   - bf2f(h0));
        ushort_t l1 = f2bf_rne(v[2*j+1] - bf2f(h1));
        hh[j] = (unsigned)h0 | ((unsigned)h1 << 16);
        ll[j] = (unsigned)l0 | ((unsigned)l1 << 16);
    }
    *H = (uint4){hh[0], hh[1], hh[2], hh[3]};
    *L = (uint4){ll[0], ll[1], ll[2], ll[3]};
}
// 8 fp32 -> 8 bf16 (hi only). R9 post-mortem: this pack VALU between load and
// barrier hides load latency — do not replace with bare copies.
__device__ inline uint4 pack8hi(float4 a0, float4 a1) {
    float v[8] = {a0.x, a0.y, a0.z, a0.w, a1.x, a1.y, a1.z, a1.w};
    unsigned hh[4];
    #pragma unroll
    for (int j = 0; j < 4; j++)
        hh[j] = (unsigned)f2bf_rne(v[2*j]) | ((unsigned)f2bf_rne(v[2*j+1]) << 16);
    return (uint4){hh[0], hh[1], hh[2], hh[3]};
}

// ---------------------------------------------------------------------------
// split_f32: A (fp32) -> hi/lo bf16 arrays. 8 elems/thread.
// ---------------------------------------------------------------------------
__global__ __launch_bounds__(256)
void split_f32(const float* __restrict__ A, ushort_t* __restrict__ hi,
               ushort_t* __restrict__ lo)
{
    const size_t base = ((size_t)blockIdx.x * 256 + threadIdx.x) * 8;
    uint4 H, L;
    split8(*(const float4*)(A + base), *(const float4*)(A + base + 4), &H, &L);
    *(uint4*)(hi + base) = H;
    *(uint4*)(lo + base) = L;
}

// ---------------------------------------------------------------------------
// split_transpose: W[K][N] fp32 -> Thi/Tlo[N][K] bf16 (64x64 tiles via LDS).
// ---------------------------------------------------------------------------
__global__ __launch_bounds__(256)
void split_transpose(const float* __restrict__ W, ushort_t* __restrict__ Thi,
                     ushort_t* __restrict__ Tlo, int Kdim, int Ndim)
{
    __shared__ float Ws[64][65];
    const int tid = threadIdx.x;
    const int k0 = blockIdx.x * 64;
    const int n0 = blockIdx.y * 64;
    const int r  = tid >> 4;
    const int c4 = (tid & 15) * 4;
    #pragma unroll
    for (int i = 0; i < 4; i++) {
        float4 v = *(const float4*)(W + (size_t)(k0 + r + i*16) * Ndim + n0 + c4);
        Ws[r + i*16][c4+0] = v.x;
        Ws[r + i*16][c4+1] = v.y;
        Ws[r + i*16][c4+2] = v.z;
        Ws[r + i*16][c4+3] = v.w;
    }
    __syncthreads();
    #pragma unroll
    for (int i = 0; i < 4; i++) {
        const int nl = r + i*16;
        ushort_t h[4], l[4];
        #pragma unroll
        for (int j = 0; j < 4; j++) {
            float x = Ws[c4 + j][nl];
            h[j] = f2bf_rne(x);
            l[j] = f2bf_rne(x - bf2f(h[j]));
        }
        size_t off = (size_t)(n0 + nl) * Kdim + k0 + c4;
        uint2 H, L;
        H.x = (unsigned)h[0] | ((unsigned)h[1] << 16);
        H.y = (unsigned)h[2] | ((unsigned)h[3] << 16);
        L.x = (unsigned)l[0] | ((unsigned)l[1] << 16);
        L.y = (unsigned)l[2] | ((unsigned)l[3] << 16);
        *(uint2*)(Thi + off) = H;
        *(uint2*)(Tlo + off) = L;
    }
}

// ---------------------------------------------------------------------------
// prep_pvt: posV fp32 [257][64] -> global pvT bf16 [64 d][LDPV r].
// ---------------------------------------------------------------------------
__global__ __launch_bounds__(256)
void prep_pvt(const float* __restrict__ posV, ushort_t* __restrict__ pvTg)
{
    __shared__ float Ws[64][65];
    const int tid = threadIdx.x;
    const int c = blockIdx.x;
    {
        const int r  = tid >> 2;
        const int d0 = (tid & 3) * 16;
        const float* src = posV + (size_t)(c * 64 + r + 1) * 64 + d0;
        #pragma unroll
        for (int i = 0; i < 4; i++) {
            float4 v = *(const float4*)(src + i * 4);
            Ws[r][d0 + i*4 + 0] = v.x;
            Ws[r][d0 + i*4 + 1] = v.y;
            Ws[r][d0 + i*4 + 2] = v.z;
            Ws[r][d0 + i*4 + 3] = v.w;
        }
    }
    __syncthreads();
    {
        const int d  = tid >> 2;
        const int r0 = (tid & 3) * 16;
        #pragma unroll
        for (int k = 0; k < 16; k++)
            pvTg[(size_t)d * LDPV + c * 64 + r0 + k] = f2bf_rne(Ws[r0 + k][d]);
    }
}

// ---------------------------------------------------------------------------
// gemm_mfma (R8-proven 64-tile): C = A @ B + bias, split-bf16 3-term MFMA.
// ---------------------------------------------------------------------------
__global__ __launch_bounds__(256)
void gemm_mfma(const ushort_t* __restrict__ Ahi, const ushort_t* __restrict__ Alo,
               const ushort_t* __restrict__ Bhi, const ushort_t* __restrict__ Blo,
               const float* __restrict__ bias, float* __restrict__ C,
               int M, int N, int K, int mode)
{
    __shared__ ushort_t As[2][64 * LDK];
    __shared__ ushort_t Bs[2][64 * LDK];
    const int tid  = threadIdx.x;
    const int m0   = blockIdx.x * 64;
    const int n0   = blockIdx.y * 64;
    const int wave = tid >> 6;
    const int lane = tid & 63;
    const int w0 = wave >> 1;
    const int w1 = wave & 1;
    const int lr = lane & 15;
    const int lq = lane >> 4;

    f32x4 acc[2][2];
    #pragma unroll
    for (int i = 0; i < 2; i++)
        #pragma unroll
        for (int j = 0; j < 2; j++)
            acc[i][j] = (f32x4){0.f, 0.f, 0.f, 0.f};

    for (int k0 = 0; k0 < K; k0 += 64) {
        __syncthreads();
        #pragma unroll
        for (int c = 0; c < 2; c++) {
            const int n   = c * 256 + tid;
            const int row = n >> 3;
            const int col = (n & 7) * 8;
            const size_t ga = (size_t)(m0 + row) * K + k0 + col;
            const size_t gb = (size_t)(n0 + row) * K + k0 + col;
            const int la = row * LDK + col;
            *(uint4*)&As[0][la] = *(const uint4*)(Ahi + ga);
            *(uint4*)&As[1][la] = *(const uint4*)(Alo + ga);
            *(uint4*)&Bs[0][la] = *(const uint4*)(Bhi + gb);
            *(uint4*)&Bs[1][la] = *(const uint4*)(Blo + gb);
        }
        __syncthreads();
        #pragma unroll
        for (int ks = 0; ks < 2; ks++) {
            bf16x8 ah[2], al[2], bh[2], bl[2];
            #pragma unroll
            for (int i = 0; i < 2; i++) {
                const int ar = (w0*32 + i*16 + lr) * LDK + ks*32 + lq*8;
                ah[i] = *(const bf16x8*)&As[0][ar];
                al[i] = *(const bf16x8*)&As[1][ar];
                const int br = (w1*32 + i*16 + lr) * LDK + ks*32 + lq*8;
                bh[i] = *(const bf16x8*)&Bs[0][br];
                bl[i] = *(const bf16x8*)&Bs[1][br];
            }
            #pragma unroll
            for (int i = 0; i < 2; i++)
                #pragma unroll
                for (int j = 0; j < 2; j++) {
                    acc[i][j] = __builtin_amdgcn_mfma_f32_16x16x32_bf16(ah[i], bh[j], acc[i][j], 0, 0, 0);
                    acc[i][j] = __builtin_amdgcn_mfma_f32_16x16x32_bf16(ah[i], bl[j], acc[i][j], 0, 0, 0);
                    acc[i][j] = __builtin_amdgcn_mfma_f32_16x16x32_bf16(al[i], bh[j], acc[i][j], 0, 0, 0);
                }
        }
    }

    #pragma unroll
    for (int j = 0; j < 2; j++) {
        const int colg = n0 + w1*32 + j*16 + lr;
        const float bcol = bias[colg];
        #pragma unroll
        for (int i = 0; i < 2; i++) {
            #pragma unroll
            for (int r = 0; r < 4; r++) {
                const int m = m0 + w0*32 + i*16 + lq*4 + r;
                const float v = acc[i][j][r] + bcol;
                if (mode == 0) {
                    C[(size_t)m * N + colg] = v;
                } else if (mode == 1) {
                    const int b = m >> 10, lp = m & 1023;
                    const int h = colg >> 6, dd = colg & 63;
                    C[((size_t)(b * NH + h) * L_SEQ + lp) * DH + dd] = v;
                } else {
                    const int b = m >> 10, lp = m & 1023;
                    const int h = colg >> 6, dd = colg & 63;
                    C[((size_t)(b * NH + h) * DH + dd) * L_SEQ + lp] = v;
                }
            }
        }
    }
}

// ---------------------------------------------------------------------------
// qp v4 (R8-proven): Qp = Q @ posK^T, fp32 math, bf16 output.
// ---------------------------------------------------------------------------
__global__ __launch_bounds__(256)
void qp_kernel(const float* __restrict__ Q, const float* __restrict__ posK,
               ushort_t* __restrict__ Qpu)
{
    __shared__ float Qt[64 * 64];
    __shared__ float Pt[64 * 64];
    const int tid = threadIdx.x;
    const size_t gq0 = (size_t)blockIdx.x * 64;
    const int ty = tid >> 4;
    const int tx = tid & 15;

    {
        const int q  = tid >> 2;
        const int d0 = (tid & 3) * 16;
        const float* qrow = Q + (gq0 + q) * DH + d0;
        #pragma unroll
        for (int i = 0; i < 4; i++) {
            float4 v = *(const float4*)(qrow + i * 4);
            Qt[(d0 + i*4 + 0) * 64 + q] = v.x;
            Qt[(d0 + i*4 + 1) * 64 + q] = v.y;
            Qt[(d0 + i*4 + 2) * 64 + q] = v.z;
            Qt[(d0 + i*4 + 3) * 64 + q] = v.w;
        }
    }

    for (int c = 0; c < 4; c++) {
        __syncthreads();
        {
            const int r  = tid >> 2;
            const int d0 = (tid & 3) * 16;
            const float* krow = posK + (size_t)(c * 64 + r) * DH + d0;
            #pragma unroll
            for (int i = 0; i < 4; i++) {
                float4 v = *(const float4*)(krow + i * 4);
                Pt[(d0 + i*4 + 0) * 64 + r] = v.x;
                Pt[(d0 + i*4 + 1) * 64 + r] = v.y;
                Pt[(d0 + i*4 + 2) * 64 + r] = v.z;
                Pt[(d0 + i*4 + 3) * 64 + r] = v.w;
            }
        }
        __syncthreads();

        float acc[16];
        #pragma unroll
        for (int i = 0; i < 16; i++) acc[i] = 0.f;
        #pragma unroll 16
        for (int d = 0; d < 64; d++) {
            float4 qv = *(const float4*)&Qt[d * 64 + ty * 4];
            float4 pv = *(const float4*)&Pt[d * 64 + tx * 4];
            float qa[4] = {qv.x, qv.y, qv.z, qv.w};
            float pa[4] = {pv.x, pv.y, pv.z, pv.w};
            #pragma unroll
            for (int i = 0; i < 4; i++)
                #pragma unroll
                for (int j = 0; j < 4; j++)
                    acc[i * 4 + j] += qa[i] * pa[j];
        }
        #pragma unroll
        for (int i = 0; i < 4; i++) {
            uint2 o;
            o.x = (unsigned)f2bf_rne(acc[i*4+0]) | ((unsigned)f2bf_rne(acc[i*4+1]) << 16);
            o.y = (unsigned)f2bf_rne(acc[i*4+2]) | ((unsigned)f2bf_rne(acc[i*4+3]) << 16);
            *(uint2*)(Qpu + (gq0 + ty * 4 + i) * QP_STRIDE + c * 64 + tx * 4) = o;
        }
    }

    __syncthreads();
    if (tid < 64) {
        float s = 0.f;
        #pragma unroll 16
        for (int d = 0; d < 64; d++)
            s += Qt[d * 64 + tid] * posK[256 * 64 + d];
        Qpu[(gq0 + tid) * QP_STRIDE + 256] = f2bf_rne(s);
    }
}

// ---------------------------------------------------------------------------
// attn v9: 2 barriers/ktile + cross-tile register prefetch.
// Waves split by q (wave w owns q-rows w*16..w*16+15, full 64-k tile):
//  - Q A-frags live in registers (loaded once; no Q LDS)
//  - P is wave-private -> P LDS round-trip needs no barrier (aliases QpsP)
//  - l/clo/chi reduced purely via shfl (no LDS red arrays)
// K/V/Qps/mask for tile t+1 are loaded into registers right after barrier
// (b), giving them a full ktile of compute before the drain at (a).
// R10 diagnosis: 4 barriers/ktile x vmcnt(0) drains ~= 70% stall.
// ---------------------------------------------------------------------------
__global__ __launch_bounds__(256)
void attn_kernel(const float* __restrict__ Q, const float* __restrict__ K,
                 const float* __restrict__ Vt, const ushort_t* __restrict__ Qpu,
                 const float* __restrict__ pm,
                 ushort_t* __restrict__ SbandU,
                 float* __restrict__ O1a, float* __restrict__ O1b,
                 float* __restrict__ lsum2, float* __restrict__ clo2,
                 float* __restrict__ chi2)
{
    __shared__ ushort_t Ks[64 * LDK];     // K-hi [k][d]
    __shared__ ushort_t Vs[64 * LDK];     // V^T-hi [d][k]
    __shared__ ushort_t QpsP[64 * LDQP];  // Qp slice [ql][kl]; P-hi aliased (wave-private rows)
    __shared__ float mk[64];

    const int tid = threadIdx.x;
    const int blk = blockIdx.x;
    const int bh  = blk >> 5;
    const int qb  = (blk >> 1) & 15;
    const int ks  = blk & 1;
    const int b   = bh >> 4;
    const int q0  = qb * 64;
    const size_t gq0 = (size_t)bh * L_SEQ + q0;
    const int wave = tid >> 6, lane = tid & 63;
    const int lr = lane & 15, lq = lane >> 4;
    const int qw = wave * 16;             // wave's local q base

    // staging geometry (block-wide, same as R8)
    const int sr0 = tid >> 3,          sc0 = (tid & 7) * 8;          // slot 0
    const int sr1 = (256 + tid) >> 3,  sc1 = ((256 + tid) & 7) * 8;  // slot 1
    // Qps prefetch geometry (wave-private rows)
    const int qpRowL = qw + (lane >> 2);          // local ql
    const int qpCol0 = (lane & 3) * 16;

    const float* Kg  = K  + (size_t)bh * (L_SEQ * DH);
    const float* Vtg = Vt + (size_t)bh * (DH * L_SEQ);

    // Q A-frags in registers (hi only), loaded once
    bf16x8 qa[2];
    {
        const float* qrow = Q + (gq0 + qw + lr) * DH;
        #pragma unroll
        for (int kc = 0; kc < 2; kc++) {
            const float* s = qrow + kc * 32 + lq * 8;
            uint4 u = pack8hi(*(const float4*)s, *(const float4*)(s + 4));
            qa[kc] = *(bf16x8*)&u;
        }
    }

    // band zero-prefill (split 0 only)
    if (ks == 0 && tid < 64) {
        const int q = q0 + tid;
        ushort_t* bandRow = SbandU + (gq0 + tid) * 256;
        for (int j = 0; j < 127 - q; j++)    bandRow[j] = 0;
        for (int j = 254; j > 1150 - q; j--) bandRow[j] = 0;
        bandRow[255] = 0;
    }

    f32x4 Oacc[4];
    #pragma unroll
    for (int j = 0; j < 4; j++) Oacc[j] = (f32x4){0.f, 0.f, 0.f, 0.f};
    float lpart[4] = {}, clpart[4] = {}, chpart[4] = {};

    // prologue: prefetch tile 0 into registers
    float4 kva[2][2], kvb[2][2];          // K, V staging data
    ushort_t qpr[16];
    float mkr = 0.f;
    {
        const int k0 = ks * 512;
        const float* ka0 = Kg + (size_t)(k0 + sr0) * DH + sc0;
        const float* ka1 = Kg + (size_t)(k0 + sr1) * DH + sc1;
        kva[0][0] = *(const float4*)ka0;      kva[0][1] = *(const float4*)(ka0 + 4);
        kva[1][0] = *(const float4*)ka1;      kva[1][1] = *(const float4*)(ka1 + 4);
        const float* va0 = Vtg + (size_t)sr0 * L_SEQ + k0 + sc0;
        const float* va1 = Vtg + (size_t)sr1 * L_SEQ + k0 + sc1;
        kvb[0][0] = *(const float4*)va0;      kvb[0][1] = *(const float4*)(va0 + 4);
        kvb[1][0] = *(const float4*)va1;      kvb[1][1] = *(const float4*)(va1 + 4);
        const int qg = q0 + qpRowL;
        #pragma unroll
        for (int c = 0; c < 16; c++) {
            int rel = k0 + qpCol0 + c - qg;
            rel = rel < -128 ? -128 : (rel > 128 ? 128 : rel);
            qpr[c] = Qpu[(gq0 + qpRowL) * QP_STRIDE + rel + 128];
        }
        if (tid < 64) mkr = pm[b * L_SEQ + k0 + tid];
    }

    for (int t = 0; t < 8; t++) {
        const int k0 = (ks * 8 + t) * 64;
        __syncthreads();   // (a) prev O-pass done with Ks/Vs; prefetch regs ready

        // write staged K/V (pack VALU fills the load-drain window), Qps, mask
        *(uint4*)&Ks[sr0 * LDK + sc0] = pack8hi(kva[0][0], kva[0][1]);
        *(uint4*)&Ks[sr1 * LDK + sc1] = pack8hi(kva[1][0], kva[1][1]);
        *(uint4*)&Vs[sr0 * LDK + sc0] = pack8hi(kvb[0][0], kvb[0][1]);
        *(uint4*)&Vs[sr1 * LDK + sc1] = pack8hi(kvb[1][0], kvb[1][1]);
        {
            ushort_t* dst = &QpsP[qpRowL * LDQP + qpCol0];
            #pragma unroll
            for (int c = 0; c < 8; c++)
                ((unsigned*)dst)[c] = (unsigned)qpr[2*c] | ((unsigned)qpr[2*c+1] << 16);
        }
        if (tid < 64) mk[tid] = mkr;
        __syncthreads();   // (b)

        // issue next tile's global loads (drain at next (a), a full ktile away)
        if (t < 7) {
            const int k0n = k0 + 64;
            const float* ka0 = Kg + (size_t)(k0n + sr0) * DH + sc0;
            const float* ka1 = Kg + (size_t)(k0n + sr1) * DH + sc1;
            kva[0][0] = *(const float4*)ka0;  kva[0][1] = *(const float4*)(ka0 + 4);
            kva[1][0] = *(const float4*)ka1;  kva[1][1] = *(const float4*)(ka1 + 4);
            const float* va0 = Vtg + (size_t)sr0 * L_SEQ + k0n + sc0;
            const float* va1 = Vtg + (size_t)sr1 * L_SEQ + k0n + sc1;
            kvb[0][0] = *(const float4*)va0;  kvb[0][1] = *(const float4*)(va0 + 4);
            kvb[1][0] = *(const float4*)va1;  kvb[1][1] = *(const float4*)(va1 + 4);
            const int qg = q0 + qpRowL;
            #pragma unroll
            for (int c = 0; c < 16; c++) {
                int rel = k0n + qpCol0 + c - qg;
                rel = rel < -128 ? -128 : (rel > 128 ? 128 : rel);
                qpr[c] = Qpu[(gq0 + qpRowL) * QP_STRIDE + rel + 128];
            }
            if (tid < 64) mkr = pm[b * L_SEQ + k0n + tid];
        }

        // S-pass: wave computes S[16q x 64k] as 4 tiles (hi-only MFMA)
        f32x4 Sacc[4];
        #pragma unroll
        for (int j = 0; j < 4; j++) Sacc[j] = (f32x4){0.f, 0.f, 0.f, 0.f};
        #pragma unroll
        for (int kc = 0; kc < 2; kc++) {
            #pragma unroll
            for (int j = 0; j < 4; j++) {
                bf16x8 kb = *(const bf16x8*)&Ks[(j*16 + lr) * LDK + kc*32 + lq*8];
                Sacc[j] = __builtin_amdgcn_mfma_f32_16x16x32_bf16(qa[kc], kb, Sacc[j], 0, 0, 0);
            }
        }

        // epilogue (C-layout: q = qw + lq*4 + r, k = j*16 + lr)
        ushort_t pb[4][4];
        #pragma unroll
        for (int r = 0; r < 4; r++) {
            const int ql = qw + lq*4 + r;
            const int q  = q0 + ql;
            const size_t gq = gq0 + ql;
            ushort_t* bandRow = SbandU + gq * 256 + 127;
            #pragma unroll
            for (int j = 0; j < 4; j++) {
                const int kl = j*16 + lr;
                const int k  = k0 + kl;
                const int rel = k - q;
                float s = (Sacc[j][r] + bf2f(QpsP[ql * LDQP + kl])) * 0.125f;
                s *= mk[kl];
                const float p = __expf(s);
                lpart[r] += p;
                const ushort_t ph = f2bf_rne(p);
                if (rel <= -128)      clpart[r] += p;
                else if (rel >= 128)  chpart[r] += p;
                else                  bandRow[rel] = ph;
                pb[j][r] = ph;
            }
        }

        // P-hi write into wave-private rows of QpsP (no barrier needed)
        #pragma unroll
        for (int r = 0; r < 4; r++)
            #pragma unroll
            for (int j = 0; j < 4; j++)
                QpsP[(qw + lq*4 + r) * LDQP + j*16 + lr] = pb[j][r];

        // O-pass: O[16q x 64d] += P[16 x 64] . V[64 x 64]
        #pragma unroll
        for (int kc = 0; kc < 2; kc++) {
            bf16x8 pa = *(const bf16x8*)&QpsP[(qw + lr) * LDQP + kc*32 + lq*8];
            #pragma unroll
            for (int j = 0; j < 4; j++) {
                bf16x8 vb = *(const bf16x8*)&Vs[(j*16 + lr) * LDK + kc*32 + lq*8];
                Oacc[j] = __builtin_amdgcn_mfma_f32_16x16x32_bf16(pa, vb, Oacc[j], 0, 0, 0);
            }
        }
    }

    // reduce l/clo/chi across lr (lane bits 0..3); wave owns its q-rows
    #pragma unroll
    for (int off = 1; off < 16; off <<= 1) {
        #pragma unroll
        for (int r = 0; r < 4; r++) {
            lpart[r]  += __shfl_xor(lpart[r],  off, 64);
            clpart[r] += __shfl_xor(clpart[r], off, 64);
            chpart[r] += __shfl_xor(chpart[r], off, 64);
        }
    }
    if (lr == 0) {
        #pragma unroll
        for (int r = 0; r < 4; r++) {
            const size_t o = (size_t)ks * GQ_TOT + gq0 + qw + lq*4 + r;
            lsum2[o] = lpart[r];
            clo2[o]  = clpart[r];
            chi2[o]  = chpart[r];
        }
    }

    // store O1 partial
    float* O1o = ks ? O1b : O1a;
    #pragma unroll
    for (int j = 0; j < 4; j++)
        #pragma unroll
        for (int r = 0; r < 4; r++)
            O1o[(gq0 + qw + lq*4 + r) * DH + j*16 + lr] = Oacc[j][r];
}

// ---------------------------------------------------------------------------
// post_mfma (R10-proven): O2 = band @ posV^T via MFMA; fused epilogue emits
// athi/atlo bf16 split directly.
// ---------------------------------------------------------------------------
__global__ __launch_bounds__(256)
void post_mfma(const ushort_t* __restrict__ SbandU, const ushort_t* __restrict__ pvTg,
               const float* __restrict__ O1a, const float* __restrict__ O1b,
               const float* __restrict__ lsum2, const float* __restrict__ clo2,
               const float* __restrict__ chi2, const float* __restrict__ posV,
               ushort_t* __restrict__ athi, ushort_t* __restrict__ atlo)
{
    __shared__ ushort_t pvT[64 * LDPV];
    const int tid = threadIdx.x;
    const size_t q0 = (size_t)blockIdx.x * 64;
    const int wave = tid >> 6, lane = tid & 63;
    const int w0 = wave >> 1, w1 = wave & 1;
    const int lr = lane & 15, lq = lane >> 4;

    {
        const unsigned* src = (const unsigned*)pvTg;
        unsigned* dst = (unsigned*)pvT;
        for (int i = tid; i < 64 * LDPV / 2; i += 256) dst[i] = src[i];
    }
    __syncthreads();

    f32x4 acc[2][2];
    #pragma unroll
    for (int i = 0; i < 2; i++)
        #pragma unroll
        for (int j = 0; j < 2; j++)
            acc[i][j] = (f32x4){0.f, 0.f, 0.f, 0.f};

    const ushort_t* bandB = SbandU + q0 * 256;
    #pragma unroll
    for (int kc = 0; kc < 8; kc++) {
        bf16x8 a[2], bv[2];
        #pragma unroll
        for (int i = 0; i < 2; i++) {
            a[i]  = *(const bf16x8*)&bandB[(size_t)(w0*32 + i*16 + lr) * 256 + kc*32 + lq*8];
            bv[i] = *(const bf16x8*)&pvT[(w1*32 + i*16 + lr) * LDPV + kc*32 + lq*8];
        }
        #pragma unroll
        for (int i = 0; i < 2; i++)
            #pragma unroll
            for (int j = 0; j < 2; j++)
                acc[i][j] = __builtin_amdgcn_mfma_f32_16x16x32_bf16(a[i], bv[j], acc[i][j], 0, 0, 0);
    }

    #pragma unroll
    for (int i = 0; i < 2; i++) {
        #pragma unroll
        for (int r = 0; r < 4; r++) {
            const int ql = w0*32 + i*16 + lq*4 + r;
            const size_t gq = q0 + ql;
            const float li = lsum2[gq] + lsum2[GQ_TOT + gq];
            const float cl = clo2[gq]  + clo2[GQ_TOT + gq];
            const float ch = chi2[gq]  + chi2[GQ_TOT + gq];
            const float inv = 1.0f / li;
            const int b  = (int)(gq >> 14);
            const int h  = (int)((gq >> 10) & 15);
            const int lp = (int)(gq & 1023);
            const size_t obase = ((size_t)(b * L_SEQ + lp) * 1024) + h * 64;
            #pragma unroll
            for (int j = 0; j < 2; j++) {
                const int dd = w1*32 + j*16 + lr;
                float o = O1a[gq * DH + dd] + O1b[gq * DH + dd] + acc[i][j][r]
                        + cl * posV[dd] + ch * posV[256 * 64 + dd];
                o *= inv;
                const ushort_t hh = f2bf_rne(o);
                const ushort_t ll = f2bf_rne(o - bf2f(hh));
                athi[obase + dd] = hh;
                atlo[obase + dd] = ll;
            }
        }
    }
}

// ---------------------------------------------------------------------------
extern "C" void kernel_launch(void* const* d_in, const int* in_sizes, int n_in,
                              void* d_out, int out_size, void* d_ws, size_t ws_size,
                              hipStream_t stream)
{
    const float* x    = (const float*)d_in[0];
    const float* pmk  = (const float*)d_in[1];
    const float* Wq   = (const float*)d_in[2];
    const float* bq   = (const float*)d_in[3];
    const float* Wk   = (const float*)d_in[4];
    const float* bk   = (const float*)d_in[5];
    const float* Wv   = (const float*)d_in[6];
    const float* bv   = (const float*)d_in[7];
    const float* Wo   = (const float*)d_in[8];
    const float* bo   = (const float*)d_in[9];
    const float* posK = (const float*)d_in[10];
    const float* posV = (const float*)d_in[11];
    float* out = (float*)d_out;

    float* ws = (float*)d_ws;
    float* Qb = ws;
    float* Kb = Qb + (size_t)GQ_TOT * DH;
    float* Vb = Kb + (size_t)GQ_TOT * DH;
    ushort_t* Qpu    = (ushort_t*)(Vb + (size_t)GQ_TOT * DH);
    ushort_t* SbandU = Qpu + (size_t)GQ_TOT * QP_STRIDE;
    ushort_t* athi   = SbandU + (size_t)GQ_TOT * 256;
    ushort_t* atlo   = athi + (size_t)GQ_TOT * DH;
    ushort_t* pvTg   = atlo + (size_t)GQ_TOT * DH;
    float* O1a   = (float*)(pvTg + 64 * LDPV);
    float* O1b   = O1a   + (size_t)GQ_TOT * DH;
    float* lsum2 = O1b   + (size_t)GQ_TOT * DH;
    float* clo2  = lsum2 + 2 * (size_t)GQ_TOT;
    float* chi2  = clo2  + 2 * (size_t)GQ_TOT;

    ushort_t* bb  = SbandU;
    ushort_t* xhi = bb;
    ushort_t* xlo = xhi + 4194304;
    ushort_t* wqh = xlo + 4194304;
    ushort_t* wql = wqh + 1048576;
    ushort_t* wkh = wql + 1048576;
    ushort_t* wkl = wkh + 1048576;
    ushort_t* wvh = wkl + 1048576;
    ushort_t* wvl = wvh + 1048576;
    ushort_t* woh = bb;
    ushort_t* wol = woh + 1048576;

    dim3 tg(16, 16), gg(64, 16), gb(256);

    split_f32<<<dim3(2048), gb, 0, stream>>>(x, xhi, xlo);
    split_transpose<<<tg, gb, 0, stream>>>(Wq, wqh, wql, 1024, 1024);
    split_transpose<<<tg, gb, 0, stream>>>(Wk, wkh, wkl, 1024, 1024);
    split_transpose<<<tg, gb, 0, stream>>>(Wv, wvh, wvl, 1024, 1024);
    prep_pvt<<<dim3(4), gb, 0, stream>>>(posV, pvTg);
    gemm_mfma<<<gg, gb, 0, stream>>>(xhi, xlo, wqh, wql, bq, Qb, 4096, 1024, 1024, 1);
    gemm_mfma<<<gg, gb, 0, stream>>>(xhi, xlo, wkh, wkl, bk, Kb, 4096, 1024, 1024, 1);
    gemm_mfma<<<gg, gb, 0, stream>>>(xhi, xlo, wvh, wvl, bv, Vb, 4096, 1024, 1024, 2);
    qp_kernel<<<dim3(GQ_TOT / 64), gb, 0, stream>>>(Qb, posK, Qpu);
    attn_kernel<<<dim3(2048), gb, 0, stream>>>(Qb, Kb, Vb, Qpu, pmk,
                                               SbandU, O1a, O1b, lsum2, clo2, chi2);
    post_mfma<<<dim3(GQ_TOT / 64), gb, 0, stream>>>(SbandU, pvTg, O1a, O1b, lsum2,
                                                    clo2, chi2, posV, athi, atlo);
    split_transpose<<<tg, gb, 0, stream>>>(Wo, woh, wol, 1024, 1024);
    gemm_mfma<<<gg, gb, 0, stream>>>(athi, atlo, woh, wol, bo, out, 4096, 1024, 1024, 0);
}

// Round 12
// 419.406 us; speedup vs baseline: 1.0667x; 1.0667x over previous
//
#include <hip/hip_runtime.h>
#include <math.h>

#define L_SEQ 1024
#define NB 4
#define NH 16
#define DH 64
#define BH_TOT (NB * NH)            // 64
#define GQ_TOT (BH_TOT * L_SEQ)     // 65536
#define NPOS 257                    // 2*128+1
#define QP_STRIDE 260               // padded Qp row stride (u16 elements)
#define LDK 72                      // LDS K-stride (bf16) for attn/gemm tiles
#define LDQP 72                     // stride for QpsP (u16; mult of 8 -> 16B-aligned b128)
#define LDPV 264                    // pvT row stride (u16)

typedef unsigned short ushort_t;
typedef __attribute__((ext_vector_type(8))) short bf16x8;
typedef __attribute__((ext_vector_type(4))) float f32x4;

__device__ inline ushort_t f2bf_rne(float x) {
    unsigned u = __float_as_uint(x);
    unsigned r = u + 0x7FFFu + ((u >> 16) & 1u);
    return (ushort_t)(r >> 16);
}
__device__ inline float bf2f(ushort_t h) {
    return __uint_as_float(((unsigned)h) << 16);
}
__device__ inline void split8(float4 a0, float4 a1, uint4* H, uint4* L) {
    float v[8] = {a0.x, a0.y, a0.z, a0.w, a1.x, a1.y, a1.z, a1.w};
    unsigned hh[4], ll[4];
    #pragma unroll
    for (int j = 0; j < 4; j++) {
        ushort_t h0 = f2bf_rne(v[2*j]),   h1 = f2bf_rne(v[2*j+1]);
        ushort_t l0 = f2bf_rne(v[2*j]   - bf2f(h0));
        ushort_t l1 = f2bf_rne(v[2*j+1] - bf2f(h1));
        hh[j] = (unsigned)h0 | ((unsigned)h1 << 16);
        ll[j] = (unsigned)l0 | ((unsigned)l1 << 16);
    }
    *H = (uint4){hh[0], hh[1], hh[2], hh[3]};
    *L = (uint4){ll[0], ll[1], ll[2], ll[3]};
}
__device__ inline uint4 pack8hi(float4 a0, float4 a1) {
    float v[8] = {a0.x, a0.y, a0.z, a0.w, a1.x, a1.y, a1.z, a1.w};
    unsigned hh[4];
    #pragma unroll
    for (int j = 0; j < 4; j++)
        hh[j] = (unsigned)f2bf_rne(v[2*j]) | ((unsigned)f2bf_rne(v[2*j+1]) << 16);
    return (uint4){hh[0], hh[1], hh[2], hh[3]};
}

// ---------------------------------------------------------------------------
// split_f32_hi: A (fp32) -> hi bf16 only (x's lo is no longer consumed:
// QKV GEMMs run 2-term A-hi; see R11 analysis).
// ---------------------------------------------------------------------------
__global__ __launch_bounds__(256)
void split_f32_hi(const float* __restrict__ A, ushort_t* __restrict__ hi)
{
    const size_t base = ((size_t)blockIdx.x * 256 + threadIdx.x) * 8;
    *(uint4*)(hi + base) =
        pack8hi(*(const float4*)(A + base), *(const float4*)(A + base + 4));
}

// ---------------------------------------------------------------------------
// split_transpose: W[K][N] fp32 -> Thi/Tlo[N][K] bf16 (64x64 tiles via LDS).
// ---------------------------------------------------------------------------
__global__ __launch_bounds__(256)
void split_transpose(const float* __restrict__ W, ushort_t* __restrict__ Thi,
                     ushort_t* __restrict__ Tlo, int Kdim, int Ndim)
{
    __shared__ float Ws[64][65];
    const int tid = threadIdx.x;
    const int k0 = blockIdx.x * 64;
    const int n0 = blockIdx.y * 64;
    const int r  = tid >> 4;
    const int c4 = (tid & 15) * 4;
    #pragma unroll
    for (int i = 0; i < 4; i++) {
        float4 v = *(const float4*)(W + (size_t)(k0 + r + i*16) * Ndim + n0 + c4);
        Ws[r + i*16][c4+0] = v.x;
        Ws[r + i*16][c4+1] = v.y;
        Ws[r + i*16][c4+2] = v.z;
        Ws[r + i*16][c4+3] = v.w;
    }
    __syncthreads();
    #pragma unroll
    for (int i = 0; i < 4; i++) {
        const int nl = r + i*16;
        ushort_t h[4], l[4];
        #pragma unroll
        for (int j = 0; j < 4; j++) {
            float x = Ws[c4 + j][nl];
            h[j] = f2bf_rne(x);
            l[j] = f2bf_rne(x - bf2f(h[j]));
        }
        size_t off = (size_t)(n0 + nl) * Kdim + k0 + c4;
        uint2 H, L;
        H.x = (unsigned)h[0] | ((unsigned)h[1] << 16);
        H.y = (unsigned)h[2] | ((unsigned)h[3] << 16);
        L.x = (unsigned)l[0] | ((unsigned)l[1] << 16);
        L.y = (unsigned)l[2] | ((unsigned)l[3] << 16);
        *(uint2*)(Thi + off) = H;
        *(uint2*)(Tlo + off) = L;
    }
}

// ---------------------------------------------------------------------------
// prep_pvt: posV fp32 [257][64] -> global pvT bf16 [64 d][LDPV r].
// ---------------------------------------------------------------------------
__global__ __launch_bounds__(256)
void prep_pvt(const float* __restrict__ posV, ushort_t* __restrict__ pvTg)
{
    __shared__ float Ws[64][65];
    const int tid = threadIdx.x;
    const int c = blockIdx.x;
    {
        const int r  = tid >> 2;
        const int d0 = (tid & 3) * 16;
        const float* src = posV + (size_t)(c * 64 + r + 1) * 64 + d0;
        #pragma unroll
        for (int i = 0; i < 4; i++) {
            float4 v = *(const float4*)(src + i * 4);
            Ws[r][d0 + i*4 + 0] = v.x;
            Ws[r][d0 + i*4 + 1] = v.y;
            Ws[r][d0 + i*4 + 2] = v.z;
            Ws[r][d0 + i*4 + 3] = v.w;
        }
    }
    __syncthreads();
    {
        const int d  = tid >> 2;
        const int r0 = (tid & 3) * 16;
        #pragma unroll
        for (int k = 0; k < 16; k++)
            pvTg[(size_t)d * LDPV + c * 64 + r0 + k] = f2bf_rne(Ws[r0 + k][d]);
    }
}

// ---------------------------------------------------------------------------
// gemm_mfma: C = A @ B + bias, split-bf16 MFMA.
// nterms=3: Ahi.Bhi + Ahi.Blo + Alo.Bhi (output-critical; final GEMM)
// nterms=2: Ahi.Bhi + Ahi.Blo (Alo never touched) — for QKV, whose results
//   get bf16-rounded in attn anyway (residual = x's bf16 trunc, negligible).
// mode 0: fp32 row-major; 1: fp32 [B,H,L,DH]; 2: u16 bf16 [B,H,L,DH];
// 3: u16 bf16 V^T [B,H,DH,L].
// ---------------------------------------------------------------------------
__global__ __launch_bounds__(256)
void gemm_mfma(const ushort_t* __restrict__ Ahi, const ushort_t* __restrict__ Alo,
               const ushort_t* __restrict__ Bhi, const ushort_t* __restrict__ Blo,
               const float* __restrict__ bias, void* __restrict__ Cout,
               int M, int N, int K, int mode, int nterms)
{
    __shared__ ushort_t As[2][64 * LDK];
    __shared__ ushort_t Bs[2][64 * LDK];
    const int tid  = threadIdx.x;
    const int m0   = blockIdx.x * 64;
    const int n0   = blockIdx.y * 64;
    const int wave = tid >> 6;
    const int lane = tid & 63;
    const int w0 = wave >> 1;
    const int w1 = wave & 1;
    const int lr = lane & 15;
    const int lq = lane >> 4;

    f32x4 acc[2][2];
    #pragma unroll
    for (int i = 0; i < 2; i++)
        #pragma unroll
        for (int j = 0; j < 2; j++)
            acc[i][j] = (f32x4){0.f, 0.f, 0.f, 0.f};

    for (int k0 = 0; k0 < K; k0 += 64) {
        __syncthreads();
        #pragma unroll
        for (int c = 0; c < 2; c++) {
            const int n   = c * 256 + tid;
            const int row = n >> 3;
            const int col = (n & 7) * 8;
            const size_t ga = (size_t)(m0 + row) * K + k0 + col;
            const size_t gb = (size_t)(n0 + row) * K + k0 + col;
            const int la = row * LDK + col;
            *(uint4*)&As[0][la] = *(const uint4*)(Ahi + ga);
            if (nterms == 3)
                *(uint4*)&As[1][la] = *(const uint4*)(Alo + ga);
            *(uint4*)&Bs[0][la] = *(const uint4*)(Bhi + gb);
            *(uint4*)&Bs[1][la] = *(const uint4*)(Blo + gb);
        }
        __syncthreads();
        #pragma unroll
        for (int ks = 0; ks < 2; ks++) {
            bf16x8 ah[2], bh[2], bl[2];
            #pragma unroll
            for (int i = 0; i < 2; i++) {
                const int ar = (w0*32 + i*16 + lr) * LDK + ks*32 + lq*8;
                ah[i] = *(const bf16x8*)&As[0][ar];
                const int br = (w1*32 + i*16 + lr) * LDK + ks*32 + lq*8;
                bh[i] = *(const bf16x8*)&Bs[0][br];
                bl[i] = *(const bf16x8*)&Bs[1][br];
            }
            #pragma unroll
            for (int i = 0; i < 2; i++)
                #pragma unroll
                for (int j = 0; j < 2; j++) {
                    acc[i][j] = __builtin_amdgcn_mfma_f32_16x16x32_bf16(ah[i], bh[j], acc[i][j], 0, 0, 0);
                    acc[i][j] = __builtin_amdgcn_mfma_f32_16x16x32_bf16(ah[i], bl[j], acc[i][j], 0, 0, 0);
                }
            if (nterms == 3) {
                bf16x8 al[2];
                #pragma unroll
                for (int i = 0; i < 2; i++)
                    al[i] = *(const bf16x8*)&As[1][(w0*32 + i*16 + lr) * LDK + ks*32 + lq*8];
                #pragma unroll
                for (int i = 0; i < 2; i++)
                    #pragma unroll
                    for (int j = 0; j < 2; j++)
                        acc[i][j] = __builtin_amdgcn_mfma_f32_16x16x32_bf16(al[i], bh[j], acc[i][j], 0, 0, 0);
            }
        }
    }

    #pragma unroll
    for (int j = 0; j < 2; j++) {
        const int colg = n0 + w1*32 + j*16 + lr;
        const float bcol = bias[colg];
        #pragma unroll
        for (int i = 0; i < 2; i++) {
            #pragma unroll
            for (int r = 0; r < 4; r++) {
                const int m = m0 + w0*32 + i*16 + lq*4 + r;
                const float v = acc[i][j][r] + bcol;
                if (mode == 0) {
                    ((float*)Cout)[(size_t)m * N + colg] = v;
                } else if (mode == 1) {
                    const int b = m >> 10, lp = m & 1023;
                    const int h = colg >> 6, dd = colg & 63;
                    ((float*)Cout)[((size_t)(b * NH + h) * L_SEQ + lp) * DH + dd] = v;
                } else if (mode == 2) {
                    const int b = m >> 10, lp = m & 1023;
                    const int h = colg >> 6, dd = colg & 63;
                    ((ushort_t*)Cout)[((size_t)(b * NH + h) * L_SEQ + lp) * DH + dd] = f2bf_rne(v);
                } else {
                    const int b = m >> 10, lp = m & 1023;
                    const int h = colg >> 6, dd = colg & 63;
                    ((ushort_t*)Cout)[((size_t)(b * NH + h) * DH + dd) * L_SEQ + lp] = f2bf_rne(v);
                }
            }
        }
    }
}

// ---------------------------------------------------------------------------
// qp v4 (R8-proven): Qp = Q @ posK^T, fp32 math, bf16 output.
// ---------------------------------------------------------------------------
__global__ __launch_bounds__(256)
void qp_kernel(const float* __restrict__ Q, const float* __restrict__ posK,
               ushort_t* __restrict__ Qpu)
{
    __shared__ float Qt[64 * 64];
    __shared__ float Pt[64 * 64];
    const int tid = threadIdx.x;
    const size_t gq0 = (size_t)blockIdx.x * 64;
    const int ty = tid >> 4;
    const int tx = tid & 15;

    {
        const int q  = tid >> 2;
        const int d0 = (tid & 3) * 16;
        const float* qrow = Q + (gq0 + q) * DH + d0;
        #pragma unroll
        for (int i = 0; i < 4; i++) {
            float4 v = *(const float4*)(qrow + i * 4);
            Qt[(d0 + i*4 + 0) * 64 + q] = v.x;
            Qt[(d0 + i*4 + 1) * 64 + q] = v.y;
            Qt[(d0 + i*4 + 2) * 64 + q] = v.z;
            Qt[(d0 + i*4 + 3) * 64 + q] = v.w;
        }
    }

    for (int c = 0; c < 4; c++) {
        __syncthreads();
        {
            const int r  = tid >> 2;
            const int d0 = (tid & 3) * 16;
            const float* krow = posK + (size_t)(c * 64 + r) * DH + d0;
            #pragma unroll
            for (int i = 0; i < 4; i++) {
                float4 v = *(const float4*)(krow + i * 4);
                Pt[(d0 + i*4 + 0) * 64 + r] = v.x;
                Pt[(d0 + i*4 + 1) * 64 + r] = v.y;
                Pt[(d0 + i*4 + 2) * 64 + r] = v.z;
                Pt[(d0 + i*4 + 3) * 64 + r] = v.w;
            }
        }
        __syncthreads();

        float acc[16];
        #pragma unroll
        for (int i = 0; i < 16; i++) acc[i] = 0.f;
        #pragma unroll 16
        for (int d = 0; d < 64; d++) {
            float4 qv = *(const float4*)&Qt[d * 64 + ty * 4];
            float4 pv = *(const float4*)&Pt[d * 64 + tx * 4];
            float qa[4] = {qv.x, qv.y, qv.z, qv.w};
            float pa[4] = {pv.x, pv.y, pv.z, pv.w};
            #pragma unroll
            for (int i = 0; i < 4; i++)
                #pragma unroll
                for (int j = 0; j < 4; j++)
                    acc[i * 4 + j] += qa[i] * pa[j];
        }
        #pragma unroll
        for (int i = 0; i < 4; i++) {
            uint2 o;
            o.x = (unsigned)f2bf_rne(acc[i*4+0]) | ((unsigned)f2bf_rne(acc[i*4+1]) << 16);
            o.y = (unsigned)f2bf_rne(acc[i*4+2]) | ((unsigned)f2bf_rne(acc[i*4+3]) << 16);
            *(uint2*)(Qpu + (gq0 + ty * 4 + i) * QP_STRIDE + c * 64 + tx * 4) = o;
        }
    }

    __syncthreads();
    if (tid < 64) {
        float s = 0.f;
        #pragma unroll 16
        for (int d = 0; d < 64; d++)
            s += Qt[d * 64 + tid] * posK[256 * 64 + d];
        Qpu[(gq0 + tid) * QP_STRIDE + 256] = f2bf_rne(s);
    }
}

// ---------------------------------------------------------------------------
// attn v10 = v9 structure (q-split waves, 2 barriers/ktile, cross-tile
// register prefetch) + pre-packed bf16 K/V^T from the GEMM epilogues.
// The prefetch (issued after barrier (b), consumed at next (a)) provides the
// latency cover that pack8hi used to provide in R8's v6 — this is the safe
// version of R9's failed change. Staging VALU (~25us device-wide) removed,
// K/V FETCH halved, prefetch registers halved.
// ---------------------------------------------------------------------------
__global__ __launch_bounds__(256)
void attn_kernel(const float* __restrict__ Q, const ushort_t* __restrict__ Ku,
                 const ushort_t* __restrict__ Vtu, const ushort_t* __restrict__ Qpu,
                 const float* __restrict__ pm,
                 ushort_t* __restrict__ SbandU,
                 float* __restrict__ O1a, float* __restrict__ O1b,
                 float* __restrict__ lsum2, float* __restrict__ clo2,
                 float* __restrict__ chi2)
{
    __shared__ ushort_t Ks[64 * LDK];     // K-hi [k][d]
    __shared__ ushort_t Vs[64 * LDK];     // V^T-hi [d][k]
    __shared__ ushort_t QpsP[64 * LDQP];  // Qp slice [ql][kl]; P-hi aliased (wave-private rows)
    __shared__ float mk[64];

    const int tid = threadIdx.x;
    const int blk = blockIdx.x;
    const int bh  = blk >> 5;
    const int qb  = (blk >> 1) & 15;
    const int ks  = blk & 1;
    const int b   = bh >> 4;
    const int q0  = qb * 64;
    const size_t gq0 = (size_t)bh * L_SEQ + q0;
    const int wave = tid >> 6, lane = tid & 63;
    const int lr = lane & 15, lq = lane >> 4;
    const int qw = wave * 16;             // wave's local q base

    // staging geometry: 512 uint4 slots (8 u16 each) per 64x64 u16 tile
    const int sr0 = tid >> 3,          sc0 = (tid & 7) * 8;
    const int sr1 = (256 + tid) >> 3,  sc1 = ((256 + tid) & 7) * 8;
    const int qpRowL = qw + (lane >> 2);
    const int qpCol0 = (lane & 3) * 16;

    const ushort_t* Kg  = Ku  + (size_t)bh * (L_SEQ * DH);
    const ushort_t* Vtg = Vtu + (size_t)bh * (DH * L_SEQ);

    // Q A-frags in registers (hi only), loaded once from fp32 Q
    bf16x8 qa[2];
    {
        const float* qrow = Q + (gq0 + qw + lr) * DH;
        #pragma unroll
        for (int kc = 0; kc < 2; kc++) {
            const float* s = qrow + kc * 32 + lq * 8;
            uint4 u = pack8hi(*(const float4*)s, *(const float4*)(s + 4));
            qa[kc] = *(bf16x8*)&u;
        }
    }

    // band zero-prefill (split 0 only)
    if (ks == 0 && tid < 64) {
        const int q = q0 + tid;
        ushort_t* bandRow = SbandU + (gq0 + tid) * 256;
        for (int j = 0; j < 127 - q; j++)    bandRow[j] = 0;
        for (int j = 254; j > 1150 - q; j--) bandRow[j] = 0;
        bandRow[255] = 0;
    }

    f32x4 Oacc[4];
    #pragma unroll
    for (int j = 0; j < 4; j++) Oacc[j] = (f32x4){0.f, 0.f, 0.f, 0.f};
    float lpart[4] = {}, clpart[4] = {}, chpart[4] = {};

    // prologue: prefetch tile 0 into registers
    uint4 kva0, kva1, kvb0, kvb1;
    ushort_t qpr[16];
    float mkr = 0.f;
    {
        const int k0 = ks * 512;
        kva0 = *(const uint4*)(Kg + (size_t)(k0 + sr0) * DH + sc0);
        kva1 = *(const uint4*)(Kg + (size_t)(k0 + sr1) * DH + sc1);
        kvb0 = *(const uint4*)(Vtg + (size_t)sr0 * L_SEQ + k0 + sc0);
        kvb1 = *(const uint4*)(Vtg + (size_t)sr1 * L_SEQ + k0 + sc1);
        const int qg = q0 + qpRowL;
        #pragma unroll
        for (int c = 0; c < 16; c++) {
            int rel = k0 + qpCol0 + c - qg;
            rel = rel < -128 ? -128 : (rel > 128 ? 128 : rel);
            qpr[c] = Qpu[(gq0 + qpRowL) * QP_STRIDE + rel + 128];
        }
        if (tid < 64) mkr = pm[b * L_SEQ + k0 + tid];
    }

    for (int t = 0; t < 8; t++) {
        const int k0 = (ks * 8 + t) * 64;
        __syncthreads();   // (a) prev O-pass done with Ks/Vs; prefetch regs ready

        // write staged K/V (plain uint4), Qps, mask
        *(uint4*)&Ks[sr0 * LDK + sc0] = kva0;
        *(uint4*)&Ks[sr1 * LDK + sc1] = kva1;
        *(uint4*)&Vs[sr0 * LDK + sc0] = kvb0;
        *(uint4*)&Vs[sr1 * LDK + sc1] = kvb1;
        {
            ushort_t* dst = &QpsP[qpRowL * LDQP + qpCol0];
            #pragma unroll
            for (int c = 0; c < 8; c++)
                ((unsigned*)dst)[c] = (unsigned)qpr[2*c] | ((unsigned)qpr[2*c+1] << 16);
        }
        if (tid < 64) mk[tid] = mkr;
        __syncthreads();   // (b)

        // issue next tile's global loads (drain at next (a), a full ktile away)
        if (t < 7) {
            const int k0n = k0 + 64;
            kva0 = *(const uint4*)(Kg + (size_t)(k0n + sr0) * DH + sc0);
            kva1 = *(const uint4*)(Kg + (size_t)(k0n + sr1) * DH + sc1);
            kvb0 = *(const uint4*)(Vtg + (size_t)sr0 * L_SEQ + k0n + sc0);
            kvb1 = *(const uint4*)(Vtg + (size_t)sr1 * L_SEQ + k0n + sc1);
            const int qg = q0 + qpRowL;
            #pragma unroll
            for (int c = 0; c < 16; c++) {
                int rel = k0n + qpCol0 + c - qg;
                rel = rel < -128 ? -128 : (rel > 128 ? 128 : rel);
                qpr[c] = Qpu[(gq0 + qpRowL) * QP_STRIDE + rel + 128];
            }
            if (tid < 64) mkr = pm[b * L_SEQ + k0n + tid];
        }

        // S-pass: wave computes S[16q x 64k] as 4 tiles (hi-only MFMA)
        f32x4 Sacc[4];
        #pragma unroll
        for (int j = 0; j < 4; j++) Sacc[j] = (f32x4){0.f, 0.f, 0.f, 0.f};
        #pragma unroll
        for (int kc = 0; kc < 2; kc++) {
            #pragma unroll
            for (int j = 0; j < 4; j++) {
                bf16x8 kb = *(const bf16x8*)&Ks[(j*16 + lr) * LDK + kc*32 + lq*8];
                Sacc[j] = __builtin_amdgcn_mfma_f32_16x16x32_bf16(qa[kc], kb, Sacc[j], 0, 0, 0);
            }
        }

        // epilogue (C-layout: q = qw + lq*4 + r, k = j*16 + lr)
        ushort_t pb[4][4];
        #pragma unroll
        for (int r = 0; r < 4; r++) {
            const int ql = qw + lq*4 + r;
            const int q  = q0 + ql;
            const size_t gq = gq0 + ql;
            ushort_t* bandRow = SbandU + gq * 256 + 127;
            #pragma unroll
            for (int j = 0; j < 4; j++) {
                const int kl = j*16 + lr;
                const int k  = k0 + kl;
                const int rel = k - q;
                float s = (Sacc[j][r] + bf2f(QpsP[ql * LDQP + kl])) * 0.125f;
                s *= mk[kl];
                const float p = __expf(s);
                lpart[r] += p;
                const ushort_t ph = f2bf_rne(p);
                if (rel <= -128)      clpart[r] += p;
                else if (rel >= 128)  chpart[r] += p;
                else                  bandRow[rel] = ph;
                pb[j][r] = ph;
            }
        }

        // P-hi write into wave-private rows of QpsP (no barrier needed)
        #pragma unroll
        for (int r = 0; r < 4; r++)
            #pragma unroll
            for (int j = 0; j < 4; j++)
                QpsP[(qw + lq*4 + r) * LDQP + j*16 + lr] = pb[j][r];

        // O-pass: O[16q x 64d] += P[16 x 64] . V[64 x 64]
        #pragma unroll
        for (int kc = 0; kc < 2; kc++) {
            bf16x8 pa = *(const bf16x8*)&QpsP[(qw + lr) * LDQP + kc*32 + lq*8];
            #pragma unroll
            for (int j = 0; j < 4; j++) {
                bf16x8 vb = *(const bf16x8*)&Vs[(j*16 + lr) * LDK + kc*32 + lq*8];
                Oacc[j] = __builtin_amdgcn_mfma_f32_16x16x32_bf16(pa, vb, Oacc[j], 0, 0, 0);
            }
        }
    }

    // reduce l/clo/chi across lr (lane bits 0..3); wave owns its q-rows
    #pragma unroll
    for (int off = 1; off < 16; off <<= 1) {
        #pragma unroll
        for (int r = 0; r < 4; r++) {
            lpart[r]  += __shfl_xor(lpart[r],  off, 64);
            clpart[r] += __shfl_xor(clpart[r], off, 64);
            chpart[r] += __shfl_xor(chpart[r], off, 64);
        }
    }
    if (lr == 0) {
        #pragma unroll
        for (int r = 0; r < 4; r++) {
            const size_t o = (size_t)ks * GQ_TOT + gq0 + qw + lq*4 + r;
            lsum2[o] = lpart[r];
            clo2[o]  = clpart[r];
            chi2[o]  = chpart[r];
        }
    }

    // store O1 partial
    float* O1o = ks ? O1b : O1a;
    #pragma unroll
    for (int j = 0; j < 4; j++)
        #pragma unroll
        for (int r = 0; r < 4; r++)
            O1o[(gq0 + qw + lq*4 + r) * DH + j*16 + lr] = Oacc[j][r];
}

// ---------------------------------------------------------------------------
// post_mfma (R10-proven): O2 = band @ posV^T via MFMA; fused epilogue emits
// athi/atlo bf16 split directly.
// ---------------------------------------------------------------------------
__global__ __launch_bounds__(256)
void post_mfma(const ushort_t* __restrict__ SbandU, const ushort_t* __restrict__ pvTg,
               const float* __restrict__ O1a, const float* __restrict__ O1b,
               const float* __restrict__ lsum2, const float* __restrict__ clo2,
               const float* __restrict__ chi2, const float* __restrict__ posV,
               ushort_t* __restrict__ athi, ushort_t* __restrict__ atlo)
{
    __shared__ ushort_t pvT[64 * LDPV];
    const int tid = threadIdx.x;
    const size_t q0 = (size_t)blockIdx.x * 64;
    const int wave = tid >> 6, lane = tid & 63;
    const int w0 = wave >> 1, w1 = wave & 1;
    const int lr = lane & 15, lq = lane >> 4;

    {
        const unsigned* src = (const unsigned*)pvTg;
        unsigned* dst = (unsigned*)pvT;
        for (int i = tid; i < 64 * LDPV / 2; i += 256) dst[i] = src[i];
    }
    __syncthreads();

    f32x4 acc[2][2];
    #pragma unroll
    for (int i = 0; i < 2; i++)
        #pragma unroll
        for (int j = 0; j < 2; j++)
            acc[i][j] = (f32x4){0.f, 0.f, 0.f, 0.f};

    const ushort_t* bandB = SbandU + q0 * 256;
    #pragma unroll
    for (int kc = 0; kc < 8; kc++) {
        bf16x8 a[2], bv[2];
        #pragma unroll
        for (int i = 0; i < 2; i++) {
            a[i]  = *(const bf16x8*)&bandB[(size_t)(w0*32 + i*16 + lr) * 256 + kc*32 + lq*8];
            bv[i] = *(const bf16x8*)&pvT[(w1*32 + i*16 + lr) * LDPV + kc*32 + lq*8];
        }
        #pragma unroll
        for (int i = 0; i < 2; i++)
            #pragma unroll
            for (int j = 0; j < 2; j++)
                acc[i][j] = __builtin_amdgcn_mfma_f32_16x16x32_bf16(a[i], bv[j], acc[i][j], 0, 0, 0);
    }

    #pragma unroll
    for (int i = 0; i < 2; i++) {
        #pragma unroll
        for (int r = 0; r < 4; r++) {
            const int ql = w0*32 + i*16 + lq*4 + r;
            const size_t gq = q0 + ql;
            const float li = lsum2[gq] + lsum2[GQ_TOT + gq];
            const float cl = clo2[gq]  + clo2[GQ_TOT + gq];
            const float ch = chi2[gq]  + chi2[GQ_TOT + gq];
            const float inv = 1.0f / li;
            const int b  = (int)(gq >> 14);
            const int h  = (int)((gq >> 10) & 15);
            const int lp = (int)(gq & 1023);
            const size_t obase = ((size_t)(b * L_SEQ + lp) * 1024) + h * 64;
            #pragma unroll
            for (int j = 0; j < 2; j++) {
                const int dd = w1*32 + j*16 + lr;
                float o = O1a[gq * DH + dd] + O1b[gq * DH + dd] + acc[i][j][r]
                        + cl * posV[dd] + ch * posV[256 * 64 + dd];
                o *= inv;
                const ushort_t hh = f2bf_rne(o);
                const ushort_t ll = f2bf_rne(o - bf2f(hh));
                athi[obase + dd] = hh;
                atlo[obase + dd] = ll;
            }
        }
    }
}

// ---------------------------------------------------------------------------
extern "C" void kernel_launch(void* const* d_in, const int* in_sizes, int n_in,
                              void* d_out, int out_size, void* d_ws, size_t ws_size,
                              hipStream_t stream)
{
    const float* x    = (const float*)d_in[0];
    const float* pmk  = (const float*)d_in[1];
    const float* Wq   = (const float*)d_in[2];
    const float* bq   = (const float*)d_in[3];
    const float* Wk   = (const float*)d_in[4];
    const float* bk   = (const float*)d_in[5];
    const float* Wv   = (const float*)d_in[6];
    const float* bv   = (const float*)d_in[7];
    const float* Wo   = (const float*)d_in[8];
    const float* bo   = (const float*)d_in[9];
    const float* posK = (const float*)d_in[10];
    const float* posV = (const float*)d_in[11];
    float* out = (float*)d_out;

    // workspace carve-up
    float* ws = (float*)d_ws;
    float* Qb = ws;                                           // GQ*64 f32
    ushort_t* Kbu = (ushort_t*)(Qb + (size_t)GQ_TOT * DH);    // GQ*64 u16
    ushort_t* Vtu = Kbu + (size_t)GQ_TOT * DH;                // GQ*64 u16 (V^T)
    ushort_t* Qpu = Vtu + (size_t)GQ_TOT * DH;                // GQ*260 u16
    ushort_t* SbandU = Qpu + (size_t)GQ_TOT * QP_STRIDE;      // GQ*256 u16
    ushort_t* athi = SbandU + (size_t)GQ_TOT * 256;           // GQ*64 u16
    ushort_t* atlo = athi + (size_t)GQ_TOT * DH;
    ushort_t* pvTg = atlo + (size_t)GQ_TOT * DH;              // 64*LDPV u16
    float* O1a   = (float*)(pvTg + 64 * LDPV);
    float* O1b   = O1a   + (size_t)GQ_TOT * DH;
    float* lsum2 = O1b   + (size_t)GQ_TOT * DH;
    float* clo2  = lsum2 + 2 * (size_t)GQ_TOT;
    float* chi2  = clo2  + 2 * (size_t)GQ_TOT;

    // bf16 scratch aliased into the Sband region (disjoint lifetimes):
    // phase A (xhi + QKV weight hi/lo): 10.5M u16 <= 16.78M region
    // phase B (Wo hi/lo, after post reads bands): 2.1M u16
    ushort_t* bb  = SbandU;
    ushort_t* xhi = bb;
    ushort_t* wqh = xhi + 4194304;
    ushort_t* wql = wqh + 1048576;
    ushort_t* wkh = wql + 1048576;
    ushort_t* wkl = wkh + 1048576;
    ushort_t* wvh = wkl + 1048576;
    ushort_t* wvl = wvh + 1048576;
    ushort_t* woh = bb;
    ushort_t* wol = woh + 1048576;

    dim3 tg(16, 16), gg(64, 16), gb(256);

    split_f32_hi<<<dim3(2048), gb, 0, stream>>>(x, xhi);
    split_transpose<<<tg, gb, 0, stream>>>(Wq, wqh, wql, 1024, 1024);
    split_transpose<<<tg, gb, 0, stream>>>(Wk, wkh, wkl, 1024, 1024);
    split_transpose<<<tg, gb, 0, stream>>>(Wv, wvh, wvl, 1024, 1024);
    prep_pvt<<<dim3(4), gb, 0, stream>>>(posV, pvTg);
    gemm_mfma<<<gg, gb, 0, stream>>>(xhi, xhi, wqh, wql, bq, Qb,  4096, 1024, 1024, 1, 2);
    gemm_mfma<<<gg, gb, 0, stream>>>(xhi, xhi, wkh, wkl, bk, Kbu, 4096, 1024, 1024, 2, 2);
    gemm_mfma<<<gg, gb, 0, stream>>>(xhi, xhi, wvh, wvl, bv, Vtu, 4096, 1024, 1024, 3, 2);
    qp_kernel<<<dim3(GQ_TOT / 64), gb, 0, stream>>>(Qb, posK, Qpu);
    attn_kernel<<<dim3(2048), gb, 0, stream>>>(Qb, Kbu, Vtu, Qpu, pmk,
                                               SbandU, O1a, O1b, lsum2, clo2, chi2);
    post_mfma<<<dim3(GQ_TOT / 64), gb, 0, stream>>>(SbandU, pvTg, O1a, O1b, lsum2,
                                                    clo2, chi2, posV, athi, atlo);
    split_transpose<<<tg, gb, 0, stream>>>(Wo, woh, wol, 1024, 1024);
    gemm_mfma<<<gg, gb, 0, stream>>>(athi, atlo, woh, wol, bo, out, 4096, 1024, 1024, 0, 3);
}

// Round 13
// 384.063 us; speedup vs baseline: 1.1648x; 1.0920x over previous
//
#include <hip/hip_runtime.h>
#include <math.h>

#define L_SEQ 1024
#define NB 4
#define NH 16
#define DH 64
#define BH_TOT (NB * NH)            // 64
#define GQ_TOT (BH_TOT * L_SEQ)     // 65536
#define NPOS 257                    // 2*128+1
#define QP_STRIDE 260               // padded Qp row stride (u16 elements)
#define LDK 72                      // LDS K-stride (bf16) for attn/gemm tiles
#define LDQP 72                     // stride for QpsP (u16; mult of 8 -> 16B-aligned b128)
#define LDPV 264                    // pvT row stride (u16)

typedef unsigned short ushort_t;
typedef __attribute__((ext_vector_type(8))) short bf16x8;
typedef __attribute__((ext_vector_type(4))) float f32x4;

__device__ inline ushort_t f2bf_rne(float x) {
    unsigned u = __float_as_uint(x);
    unsigned r = u + 0x7FFFu + ((u >> 16) & 1u);
    return (ushort_t)(r >> 16);
}
__device__ inline float bf2f(ushort_t h) {
    return __uint_as_float(((unsigned)h) << 16);
}
__device__ inline void split8(float4 a0, float4 a1, uint4* H, uint4* L) {
    float v[8] = {a0.x, a0.y, a0.z, a0.w, a1.x, a1.y, a1.z, a1.w};
    unsigned hh[4], ll[4];
    #pragma unroll
    for (int j = 0; j < 4; j++) {
        ushort_t h0 = f2bf_rne(v[2*j]),   h1 = f2bf_rne(v[2*j+1]);
        ushort_t l0 = f2bf_rne(v[2*j]   - bf2f(h0));
        ushort_t l1 = f2bf_rne(v[2*j+1] - bf2f(h1));
        hh[j] = (unsigned)h0 | ((unsigned)h1 << 16);
        ll[j] = (unsigned)l0 | ((unsigned)l1 << 16);
    }
    *H = (uint4){hh[0], hh[1], hh[2], hh[3]};
    *L = (uint4){ll[0], ll[1], ll[2], ll[3]};
}
__device__ inline uint4 pack8hi(float4 a0, float4 a1) {
    float v[8] = {a0.x, a0.y, a0.z, a0.w, a1.x, a1.y, a1.z, a1.w};
    unsigned hh[4];
    #pragma unroll
    for (int j = 0; j < 4; j++)
        hh[j] = (unsigned)f2bf_rne(v[2*j]) | ((unsigned)f2bf_rne(v[2*j+1]) << 16);
    return (uint4){hh[0], hh[1], hh[2], hh[3]};
}

// ---------------------------------------------------------------------------
// split_f32_hi: A (fp32) -> hi bf16 only.
// ---------------------------------------------------------------------------
__global__ __launch_bounds__(256)
void split_f32_hi(const float* __restrict__ A, ushort_t* __restrict__ hi)
{
    const size_t base = ((size_t)blockIdx.x * 256 + threadIdx.x) * 8;
    *(uint4*)(hi + base) =
        pack8hi(*(const float4*)(A + base), *(const float4*)(A + base + 4));
}

// ---------------------------------------------------------------------------
// split_transpose3: Wq/Wk/Wv (z-indexed) -> contiguous wqkv hi/lo [3072][1024].
// ---------------------------------------------------------------------------
__global__ __launch_bounds__(256)
void split_transpose3(const float* __restrict__ Wq, const float* __restrict__ Wk,
                      const float* __restrict__ Wv, ushort_t* __restrict__ Thi,
                      ushort_t* __restrict__ Tlo)
{
    __shared__ float Ws[64][65];
    const int tid = threadIdx.x;
    const int k0 = blockIdx.x * 64;
    const int n0 = blockIdx.y * 64;
    const int z  = blockIdx.z;
    const float* W = (z == 0) ? Wq : (z == 1) ? Wk : Wv;
    ushort_t* Hh = Thi + (size_t)z * 1048576;
    ushort_t* Ll = Tlo + (size_t)z * 1048576;
    const int r  = tid >> 4;
    const int c4 = (tid & 15) * 4;
    #pragma unroll
    for (int i = 0; i < 4; i++) {
        float4 v = *(const float4*)(W + (size_t)(k0 + r + i*16) * 1024 + n0 + c4);
        Ws[r + i*16][c4+0] = v.x;
        Ws[r + i*16][c4+1] = v.y;
        Ws[r + i*16][c4+2] = v.z;
        Ws[r + i*16][c4+3] = v.w;
    }
    __syncthreads();
    #pragma unroll
    for (int i = 0; i < 4; i++) {
        const int nl = r + i*16;
        ushort_t h[4], l[4];
        #pragma unroll
        for (int j = 0; j < 4; j++) {
            float x = Ws[c4 + j][nl];
            h[j] = f2bf_rne(x);
            l[j] = f2bf_rne(x - bf2f(h[j]));
        }
        size_t off = (size_t)(n0 + nl) * 1024 + k0 + c4;
        uint2 H, L;
        H.x = (unsigned)h[0] | ((unsigned)h[1] << 16);
        H.y = (unsigned)h[2] | ((unsigned)h[3] << 16);
        L.x = (unsigned)l[0] | ((unsigned)l[1] << 16);
        L.y = (unsigned)l[2] | ((unsigned)l[3] << 16);
        *(uint2*)(Hh + off) = H;
        *(uint2*)(Ll + off) = L;
    }
}

// ---------------------------------------------------------------------------
// split_transpose: single-matrix variant (Wo).
// ---------------------------------------------------------------------------
__global__ __launch_bounds__(256)
void split_transpose(const float* __restrict__ W, ushort_t* __restrict__ Thi,
                     ushort_t* __restrict__ Tlo, int Kdim, int Ndim)
{
    __shared__ float Ws[64][65];
    const int tid = threadIdx.x;
    const int k0 = blockIdx.x * 64;
    const int n0 = blockIdx.y * 64;
    const int r  = tid >> 4;
    const int c4 = (tid & 15) * 4;
    #pragma unroll
    for (int i = 0; i < 4; i++) {
        float4 v = *(const float4*)(W + (size_t)(k0 + r + i*16) * Ndim + n0 + c4);
        Ws[r + i*16][c4+0] = v.x;
        Ws[r + i*16][c4+1] = v.y;
        Ws[r + i*16][c4+2] = v.z;
        Ws[r + i*16][c4+3] = v.w;
    }
    __syncthreads();
    #pragma unroll
    for (int i = 0; i < 4; i++) {
        const int nl = r + i*16;
        ushort_t h[4], l[4];
        #pragma unroll
        for (int j = 0; j < 4; j++) {
            float x = Ws[c4 + j][nl];
            h[j] = f2bf_rne(x);
            l[j] = f2bf_rne(x - bf2f(h[j]));
        }
        size_t off = (size_t)(n0 + nl) * Kdim + k0 + c4;
        uint2 H, L;
        H.x = (unsigned)h[0] | ((unsigned)h[1] << 16);
        H.y = (unsigned)h[2] | ((unsigned)h[3] << 16);
        L.x = (unsigned)l[0] | ((unsigned)l[1] << 16);
        L.y = (unsigned)l[2] | ((unsigned)l[3] << 16);
        *(uint2*)(Thi + off) = H;
        *(uint2*)(Tlo + off) = L;
    }
}

// ---------------------------------------------------------------------------
// prep_pvt: posV fp32 [257][64] -> global pvT bf16 [64 d][LDPV r].
// ---------------------------------------------------------------------------
__global__ __launch_bounds__(256)
void prep_pvt(const float* __restrict__ posV, ushort_t* __restrict__ pvTg)
{
    __shared__ float Ws[64][65];
    const int tid = threadIdx.x;
    const int c = blockIdx.x;
    {
        const int r  = tid >> 2;
        const int d0 = (tid & 3) * 16;
        const float* src = posV + (size_t)(c * 64 + r + 1) * 64 + d0;
        #pragma unroll
        for (int i = 0; i < 4; i++) {
            float4 v = *(const float4*)(src + i * 4);
            Ws[r][d0 + i*4 + 0] = v.x;
            Ws[r][d0 + i*4 + 1] = v.y;
            Ws[r][d0 + i*4 + 2] = v.z;
            Ws[r][d0 + i*4 + 3] = v.w;
        }
    }
    __syncthreads();
    {
        const int d  = tid >> 2;
        const int r0 = (tid & 3) * 16;
        #pragma unroll
        for (int k = 0; k < 16; k++)
            pvTg[(size_t)d * LDPV + c * 64 + r0 + k] = f2bf_rne(Ws[r0 + k][d]);
    }
}

// ---------------------------------------------------------------------------
// gemm_qkv: fused Q/K/V projection — one launch, N=3072 (weights packed
// [3072][1024]). 2-term split MFMA (Ahi.Bhi + Ahi.Blo). Output mode is
// block-uniform (n0>>10): 0 -> Q fp32 [B,H,L,DH]; 1 -> K bf16 u16 same
// layout; 2 -> V^T bf16 u16 [B,H,DH,L]. Replaces 3 launches (each 1024
// blocks = 4/CU paid its own ramp+tail on the stream).
// ---------------------------------------------------------------------------
__global__ __launch_bounds__(256)
void gemm_qkv(const ushort_t* __restrict__ Ahi,
              const ushort_t* __restrict__ Bhi, const ushort_t* __restrict__ Blo,
              const float* __restrict__ bq, const float* __restrict__ bk,
              const float* __restrict__ bv,
              float* __restrict__ Qb, ushort_t* __restrict__ Kbu,
              ushort_t* __restrict__ Vtu)
{
    __shared__ ushort_t As[64 * LDK];
    __shared__ ushort_t Bs[2][64 * LDK];
    const int tid  = threadIdx.x;
    const int m0   = blockIdx.x * 64;
    const int n0   = blockIdx.y * 64;
    const int nb   = n0 >> 10;               // 0=Q, 1=K, 2=V (block-uniform)
    const int wave = tid >> 6, lane = tid & 63;
    const int w0 = wave >> 1, w1 = wave & 1;
    const int lr = lane & 15, lq = lane >> 4;
    const int K = 1024;

    f32x4 acc[2][2];
    #pragma unroll
    for (int i = 0; i < 2; i++)
        #pragma unroll
        for (int j = 0; j < 2; j++)
            acc[i][j] = (f32x4){0.f, 0.f, 0.f, 0.f};

    for (int k0 = 0; k0 < K; k0 += 64) {
        __syncthreads();
        #pragma unroll
        for (int c = 0; c < 2; c++) {
            const int n   = c * 256 + tid;
            const int row = n >> 3;
            const int col = (n & 7) * 8;
            const size_t ga = (size_t)(m0 + row) * K + k0 + col;
            const size_t gb = (size_t)(n0 + row) * K + k0 + col;
            const int la = row * LDK + col;
            *(uint4*)&As[la]    = *(const uint4*)(Ahi + ga);
            *(uint4*)&Bs[0][la] = *(const uint4*)(Bhi + gb);
            *(uint4*)&Bs[1][la] = *(const uint4*)(Blo + gb);
        }
        __syncthreads();
        #pragma unroll
        for (int ks = 0; ks < 2; ks++) {
            bf16x8 ah[2], bh[2], bl[2];
            #pragma unroll
            for (int i = 0; i < 2; i++) {
                const int ar = (w0*32 + i*16 + lr) * LDK + ks*32 + lq*8;
                ah[i] = *(const bf16x8*)&As[ar];
                const int br = (w1*32 + i*16 + lr) * LDK + ks*32 + lq*8;
                bh[i] = *(const bf16x8*)&Bs[0][br];
                bl[i] = *(const bf16x8*)&Bs[1][br];
            }
            #pragma unroll
            for (int i = 0; i < 2; i++)
                #pragma unroll
                for (int j = 0; j < 2; j++) {
                    acc[i][j] = __builtin_amdgcn_mfma_f32_16x16x32_bf16(ah[i], bh[j], acc[i][j], 0, 0, 0);
                    acc[i][j] = __builtin_amdgcn_mfma_f32_16x16x32_bf16(ah[i], bl[j], acc[i][j], 0, 0, 0);
                }
        }
    }

    const float* bp = (nb == 0) ? bq : (nb == 1) ? bk : bv;
    #pragma unroll
    for (int j = 0; j < 2; j++) {
        const int colg = n0 + w1*32 + j*16 + lr;
        const int c1   = colg & 1023;
        const float bcol = bp[c1];
        const int h = c1 >> 6, dd = c1 & 63;
        #pragma unroll
        for (int i = 0; i < 2; i++) {
            #pragma unroll
            for (int r = 0; r < 4; r++) {
                const int m = m0 + w0*32 + i*16 + lq*4 + r;
                const float v = acc[i][j][r] + bcol;
                const int b = m >> 10, lp = m & 1023;
                if (nb == 0)
                    Qb[((size_t)(b * NH + h) * L_SEQ + lp) * DH + dd] = v;
                else if (nb == 1)
                    Kbu[((size_t)(b * NH + h) * L_SEQ + lp) * DH + dd] = f2bf_rne(v);
                else
                    Vtu[((size_t)(b * NH + h) * DH + dd) * L_SEQ + lp] = f2bf_rne(v);
            }
        }
    }
}

// ---------------------------------------------------------------------------
// gemm_mfma: final output GEMM, 3-term split (output-critical), fp32 out.
// ---------------------------------------------------------------------------
__global__ __launch_bounds__(256)
void gemm_mfma(const ushort_t* __restrict__ Ahi, const ushort_t* __restrict__ Alo,
               const ushort_t* __restrict__ Bhi, const ushort_t* __restrict__ Blo,
               const float* __restrict__ bias, float* __restrict__ C,
               int M, int N, int K)
{
    __shared__ ushort_t As[2][64 * LDK];
    __shared__ ushort_t Bs[2][64 * LDK];
    const int tid  = threadIdx.x;
    const int m0   = blockIdx.x * 64;
    const int n0   = blockIdx.y * 64;
    const int wave = tid >> 6, lane = tid & 63;
    const int w0 = wave >> 1, w1 = wave & 1;
    const int lr = lane & 15, lq = lane >> 4;

    f32x4 acc[2][2];
    #pragma unroll
    for (int i = 0; i < 2; i++)
        #pragma unroll
        for (int j = 0; j < 2; j++)
            acc[i][j] = (f32x4){0.f, 0.f, 0.f, 0.f};

    for (int k0 = 0; k0 < K; k0 += 64) {
        __syncthreads();
        #pragma unroll
        for (int c = 0; c < 2; c++) {
            const int n   = c * 256 + tid;
            const int row = n >> 3;
            const int col = (n & 7) * 8;
            const size_t ga = (size_t)(m0 + row) * K + k0 + col;
            const size_t gb = (size_t)(n0 + row) * K + k0 + col;
            const int la = row * LDK + col;
            *(uint4*)&As[0][la] = *(const uint4*)(Ahi + ga);
            *(uint4*)&As[1][la] = *(const uint4*)(Alo + ga);
            *(uint4*)&Bs[0][la] = *(const uint4*)(Bhi + gb);
            *(uint4*)&Bs[1][la] = *(const uint4*)(Blo + gb);
        }
        __syncthreads();
        #pragma unroll
        for (int ks = 0; ks < 2; ks++) {
            bf16x8 ah[2], al[2], bh[2], bl[2];
            #pragma unroll
            for (int i = 0; i < 2; i++) {
                const int ar = (w0*32 + i*16 + lr) * LDK + ks*32 + lq*8;
                ah[i] = *(const bf16x8*)&As[0][ar];
                al[i] = *(const bf16x8*)&As[1][ar];
                const int br = (w1*32 + i*16 + lr) * LDK + ks*32 + lq*8;
                bh[i] = *(const bf16x8*)&Bs[0][br];
                bl[i] = *(const bf16x8*)&Bs[1][br];
            }
            #pragma unroll
            for (int i = 0; i < 2; i++)
                #pragma unroll
                for (int j = 0; j < 2; j++) {
                    acc[i][j] = __builtin_amdgcn_mfma_f32_16x16x32_bf16(ah[i], bh[j], acc[i][j], 0, 0, 0);
                    acc[i][j] = __builtin_amdgcn_mfma_f32_16x16x32_bf16(ah[i], bl[j], acc[i][j], 0, 0, 0);
                    acc[i][j] = __builtin_amdgcn_mfma_f32_16x16x32_bf16(al[i], bh[j], acc[i][j], 0, 0, 0);
                }
        }
    }

    #pragma unroll
    for (int j = 0; j < 2; j++) {
        const int colg = n0 + w1*32 + j*16 + lr;
        const float bcol = bias[colg];
        #pragma unroll
        for (int i = 0; i < 2; i++) {
            #pragma unroll
            for (int r = 0; r < 4; r++) {
                const int m = m0 + w0*32 + i*16 + lq*4 + r;
                C[(size_t)m * N + colg] = acc[i][j][r] + bcol;
            }
        }
    }
}

// ---------------------------------------------------------------------------
// qp_mfma: Qp[65536 x 257] = Q @ posK^T via MFMA, no LDS. A-frags packed
// straight from fp32 Q, B-frags straight from posK (L2-resident). Replaces
// the ~30us scalar-VALU qp. Grid (1024, 5); n-tile 4 stores col 256 only.
// Precision: Q/posK bf16-hi adds ~5e-5 to s (attn already rounds Q to hi).
// ---------------------------------------------------------------------------
__global__ __launch_bounds__(256)
void qp_mfma(const float* __restrict__ Q, const float* __restrict__ posK,
             ushort_t* __restrict__ Qpu)
{
    const int tid = threadIdx.x;
    const size_t m0 = (size_t)blockIdx.x * 64;
    const int n0 = blockIdx.y * 64;
    const int wave = tid >> 6, lane = tid & 63;
    const int wm = (wave >> 1) * 32, wn = (wave & 1) * 32;
    const int lr = lane & 15, lq = lane >> 4;

    // A-frags: rows m0+wm+i*16+lr, k = kc*32+lq*8 .. +8
    bf16x8 af[2][2];
    #pragma unroll
    for (int i = 0; i < 2; i++) {
        const float* qrow = Q + (m0 + wm + i*16 + lr) * DH;
        #pragma unroll
        for (int kc = 0; kc < 2; kc++) {
            const float* s = qrow + kc*32 + lq*8;
            uint4 u = pack8hi(*(const float4*)s, *(const float4*)(s + 4));
            af[i][kc] = *(bf16x8*)&u;
        }
    }
    // B-frags: posK rows n (clamped to 256 for OOB lanes; stores guarded)
    bf16x8 bf[2][2];
    #pragma unroll
    for (int j = 0; j < 2; j++) {
        int n = n0 + wn + j*16 + lr;
        const float* krow = posK + (size_t)(n < 256 ? n : 256) * DH;
        #pragma unroll
        for (int kc = 0; kc < 2; kc++) {
            const float* s = krow + kc*32 + lq*8;
            uint4 u = pack8hi(*(const float4*)s, *(const float4*)(s + 4));
            bf[j][kc] = *(bf16x8*)&u;
        }
    }

    f32x4 acc[2][2];
    #pragma unroll
    for (int i = 0; i < 2; i++)
        #pragma unroll
        for (int j = 0; j < 2; j++)
            acc[i][j] = (f32x4){0.f, 0.f, 0.f, 0.f};
    #pragma unroll
    for (int kc = 0; kc < 2; kc++)
        #pragma unroll
        for (int i = 0; i < 2; i++)
            #pragma unroll
            for (int j = 0; j < 2; j++)
                acc[i][j] = __builtin_amdgcn_mfma_f32_16x16x32_bf16(af[i][kc], bf[j][kc], acc[i][j], 0, 0, 0);

    #pragma unroll
    for (int i = 0; i < 2; i++)
        #pragma unroll
        for (int j = 0; j < 2; j++) {
            const int n = n0 + wn + j*16 + lr;
            if (n < NPOS) {
                #pragma unroll
                for (int r = 0; r < 4; r++) {
                    const size_t m = m0 + wm + i*16 + lq*4 + r;
                    Qpu[m * QP_STRIDE + n] = f2bf_rne(acc[i][j][r]);
                }
            }
        }
}

// ---------------------------------------------------------------------------
// attn v10 (R11-proven, 125us): q-split waves, 2 barriers/ktile, cross-tile
// register prefetch, pre-packed bf16 K/V^T, bf16 p-band, 2-way k-split.
// ---------------------------------------------------------------------------
__global__ __launch_bounds__(256)
void attn_kernel(const float* __restrict__ Q, const ushort_t* __restrict__ Ku,
                 const ushort_t* __restrict__ Vtu, const ushort_t* __restrict__ Qpu,
                 const float* __restrict__ pm,
                 ushort_t* __restrict__ SbandU,
                 float* __restrict__ O1a, float* __restrict__ O1b,
                 float* __restrict__ lsum2, float* __restrict__ clo2,
                 float* __restrict__ chi2)
{
    __shared__ ushort_t Ks[64 * LDK];
    __shared__ ushort_t Vs[64 * LDK];
    __shared__ ushort_t QpsP[64 * LDQP];
    __shared__ float mk[64];

    const int tid = threadIdx.x;
    const int blk = blockIdx.x;
    const int bh  = blk >> 5;
    const int qb  = (blk >> 1) & 15;
    const int ks  = blk & 1;
    const int b   = bh >> 4;
    const int q0  = qb * 64;
    const size_t gq0 = (size_t)bh * L_SEQ + q0;
    const int wave = tid >> 6, lane = tid & 63;
    const int lr = lane & 15, lq = lane >> 4;
    const int qw = wave * 16;

    const int sr0 = tid >> 3,          sc0 = (tid & 7) * 8;
    const int sr1 = (256 + tid) >> 3,  sc1 = ((256 + tid) & 7) * 8;
    const int qpRowL = qw + (lane >> 2);
    const int qpCol0 = (lane & 3) * 16;

    const ushort_t* Kg  = Ku  + (size_t)bh * (L_SEQ * DH);
    const ushort_t* Vtg = Vtu + (size_t)bh * (DH * L_SEQ);

    bf16x8 qa[2];
    {
        const float* qrow = Q + (gq0 + qw + lr) * DH;
        #pragma unroll
        for (int kc = 0; kc < 2; kc++) {
            const float* s = qrow + kc * 32 + lq * 8;
            uint4 u = pack8hi(*(const float4*)s, *(const float4*)(s + 4));
            qa[kc] = *(bf16x8*)&u;
        }
    }

    if (ks == 0 && tid < 64) {
        const int q = q0 + tid;
        ushort_t* bandRow = SbandU + (gq0 + tid) * 256;
        for (int j = 0; j < 127 - q; j++)    bandRow[j] = 0;
        for (int j = 254; j > 1150 - q; j--) bandRow[j] = 0;
        bandRow[255] = 0;
    }

    f32x4 Oacc[4];
    #pragma unroll
    for (int j = 0; j < 4; j++) Oacc[j] = (f32x4){0.f, 0.f, 0.f, 0.f};
    float lpart[4] = {}, clpart[4] = {}, chpart[4] = {};

    uint4 kva0, kva1, kvb0, kvb1;
    ushort_t qpr[16];
    float mkr = 0.f;
    {
        const int k0 = ks * 512;
        kva0 = *(const uint4*)(Kg + (size_t)(k0 + sr0) * DH + sc0);
        kva1 = *(const uint4*)(Kg + (size_t)(k0 + sr1) * DH + sc1);
        kvb0 = *(const uint4*)(Vtg + (size_t)sr0 * L_SEQ + k0 + sc0);
        kvb1 = *(const uint4*)(Vtg + (size_t)sr1 * L_SEQ + k0 + sc1);
        const int qg = q0 + qpRowL;
        #pragma unroll
        for (int c = 0; c < 16; c++) {
            int rel = k0 + qpCol0 + c - qg;
            rel = rel < -128 ? -128 : (rel > 128 ? 128 : rel);
            qpr[c] = Qpu[(gq0 + qpRowL) * QP_STRIDE + rel + 128];
        }
        if (tid < 64) mkr = pm[b * L_SEQ + k0 + tid];
    }

    for (int t = 0; t < 8; t++) {
        const int k0 = (ks * 8 + t) * 64;
        __syncthreads();   // (a)

        *(uint4*)&Ks[sr0 * LDK + sc0] = kva0;
        *(uint4*)&Ks[sr1 * LDK + sc1] = kva1;
        *(uint4*)&Vs[sr0 * LDK + sc0] = kvb0;
        *(uint4*)&Vs[sr1 * LDK + sc1] = kvb1;
        {
            ushort_t* dst = &QpsP[qpRowL * LDQP + qpCol0];
            #pragma unroll
            for (int c = 0; c < 8; c++)
                ((unsigned*)dst)[c] = (unsigned)qpr[2*c] | ((unsigned)qpr[2*c+1] << 16);
        }
        if (tid < 64) mk[tid] = mkr;
        __syncthreads();   // (b)

        if (t < 7) {
            const int k0n = k0 + 64;
            kva0 = *(const uint4*)(Kg + (size_t)(k0n + sr0) * DH + sc0);
            kva1 = *(const uint4*)(Kg + (size_t)(k0n + sr1) * DH + sc1);
            kvb0 = *(const uint4*)(Vtg + (size_t)sr0 * L_SEQ + k0n + sc0);
            kvb1 = *(const uint4*)(Vtg + (size_t)sr1 * L_SEQ + k0n + sc1);
            const int qg = q0 + qpRowL;
            #pragma unroll
            for (int c = 0; c < 16; c++) {
                int rel = k0n + qpCol0 + c - qg;
                rel = rel < -128 ? -128 : (rel > 128 ? 128 : rel);
                qpr[c] = Qpu[(gq0 + qpRowL) * QP_STRIDE + rel + 128];
            }
            if (tid < 64) mkr = pm[b * L_SEQ + k0n + tid];
        }

        f32x4 Sacc[4];
        #pragma unroll
        for (int j = 0; j < 4; j++) Sacc[j] = (f32x4){0.f, 0.f, 0.f, 0.f};
        #pragma unroll
        for (int kc = 0; kc < 2; kc++) {
            #pragma unroll
            for (int j = 0; j < 4; j++) {
                bf16x8 kb = *(const bf16x8*)&Ks[(j*16 + lr) * LDK + kc*32 + lq*8];
                Sacc[j] = __builtin_amdgcn_mfma_f32_16x16x32_bf16(qa[kc], kb, Sacc[j], 0, 0, 0);
            }
        }

        ushort_t pb[4][4];
        #pragma unroll
        for (int r = 0; r < 4; r++) {
            const int ql = qw + lq*4 + r;
            const int q  = q0 + ql;
            const size_t gq = gq0 + ql;
            ushort_t* bandRow = SbandU + gq * 256 + 127;
            #pragma unroll
            for (int j = 0; j < 4; j++) {
                const int kl = j*16 + lr;
                const int k  = k0 + kl;
                const int rel = k - q;
                float s = (Sacc[j][r] + bf2f(QpsP[ql * LDQP + kl])) * 0.125f;
                s *= mk[kl];
                const float p = __expf(s);
                lpart[r] += p;
                const ushort_t ph = f2bf_rne(p);
                if (rel <= -128)      clpart[r] += p;
                else if (rel >= 128)  chpart[r] += p;
                else                  bandRow[rel] = ph;
                pb[j][r] = ph;
            }
        }

        #pragma unroll
        for (int r = 0; r < 4; r++)
            #pragma unroll
            for (int j = 0; j < 4; j++)
                QpsP[(qw + lq*4 + r) * LDQP + j*16 + lr] = pb[j][r];

        #pragma unroll
        for (int kc = 0; kc < 2; kc++) {
            bf16x8 pa = *(const bf16x8*)&QpsP[(qw + lr) * LDQP + kc*32 + lq*8];
            #pragma unroll
            for (int j = 0; j < 4; j++) {
                bf16x8 vb = *(const bf16x8*)&Vs[(j*16 + lr) * LDK + kc*32 + lq*8];
                Oacc[j] = __builtin_amdgcn_mfma_f32_16x16x32_bf16(pa, vb, Oacc[j], 0, 0, 0);
            }
        }
    }

    #pragma unroll
    for (int off = 1; off < 16; off <<= 1) {
        #pragma unroll
        for (int r = 0; r < 4; r++) {
            lpart[r]  += __shfl_xor(lpart[r],  off, 64);
            clpart[r] += __shfl_xor(clpart[r], off, 64);
            chpart[r] += __shfl_xor(chpart[r], off, 64);
        }
    }
    if (lr == 0) {
        #pragma unroll
        for (int r = 0; r < 4; r++) {
            const size_t o = (size_t)ks * GQ_TOT + gq0 + qw + lq*4 + r;
            lsum2[o] = lpart[r];
            clo2[o]  = clpart[r];
            chi2[o]  = chpart[r];
        }
    }

    float* O1o = ks ? O1b : O1a;
    #pragma unroll
    for (int j = 0; j < 4; j++)
        #pragma unroll
        for (int r = 0; r < 4; r++)
            O1o[(gq0 + qw + lq*4 + r) * DH + j*16 + lr] = Oacc[j][r];
}

// ---------------------------------------------------------------------------
// post_mfma (R10-proven): O2 = band @ posV^T via MFMA; fused epilogue emits
// athi/atlo bf16 split directly.
// ---------------------------------------------------------------------------
__global__ __launch_bounds__(256)
void post_mfma(const ushort_t* __restrict__ SbandU, const ushort_t* __restrict__ pvTg,
               const float* __restrict__ O1a, const float* __restrict__ O1b,
               const float* __restrict__ lsum2, const float* __restrict__ clo2,
               const float* __restrict__ chi2, const float* __restrict__ posV,
               ushort_t* __restrict__ athi, ushort_t* __restrict__ atlo)
{
    __shared__ ushort_t pvT[64 * LDPV];
    const int tid = threadIdx.x;
    const size_t q0 = (size_t)blockIdx.x * 64;
    const int wave = tid >> 6, lane = tid & 63;
    const int w0 = wave >> 1, w1 = wave & 1;
    const int lr = lane & 15, lq = lane >> 4;

    {
        const unsigned* src = (const unsigned*)pvTg;
        unsigned* dst = (unsigned*)pvT;
        for (int i = tid; i < 64 * LDPV / 2; i += 256) dst[i] = src[i];
    }
    __syncthreads();

    f32x4 acc[2][2];
    #pragma unroll
    for (int i = 0; i < 2; i++)
        #pragma unroll
        for (int j = 0; j < 2; j++)
            acc[i][j] = (f32x4){0.f, 0.f, 0.f, 0.f};

    const ushort_t* bandB = SbandU + q0 * 256;
    #pragma unroll
    for (int kc = 0; kc < 8; kc++) {
        bf16x8 a[2], bv[2];
        #pragma unroll
        for (int i = 0; i < 2; i++) {
            a[i]  = *(const bf16x8*)&bandB[(size_t)(w0*32 + i*16 + lr) * 256 + kc*32 + lq*8];
            bv[i] = *(const bf16x8*)&pvT[(w1*32 + i*16 + lr) * LDPV + kc*32 + lq*8];
        }
        #pragma unroll
        for (int i = 0; i < 2; i++)
            #pragma unroll
            for (int j = 0; j < 2; j++)
                acc[i][j] = __builtin_amdgcn_mfma_f32_16x16x32_bf16(a[i], bv[j], acc[i][j], 0, 0, 0);
    }

    #pragma unroll
    for (int i = 0; i < 2; i++) {
        #pragma unroll
        for (int r = 0; r < 4; r++) {
            const int ql = w0*32 + i*16 + lq*4 + r;
            const size_t gq = q0 + ql;
            const float li = lsum2[gq] + lsum2[GQ_TOT + gq];
            const float cl = clo2[gq]  + clo2[GQ_TOT + gq];
            const float ch = chi2[gq]  + chi2[GQ_TOT + gq];
            const float inv = 1.0f / li;
            const int b  = (int)(gq >> 14);
            const int h  = (int)((gq >> 10) & 15);
            const int lp = (int)(gq & 1023);
            const size_t obase = ((size_t)(b * L_SEQ + lp) * 1024) + h * 64;
            #pragma unroll
            for (int j = 0; j < 2; j++) {
                const int dd = w1*32 + j*16 + lr;
                float o = O1a[gq * DH + dd] + O1b[gq * DH + dd] + acc[i][j][r]
                        + cl * posV[dd] + ch * posV[256 * 64 + dd];
                o *= inv;
                const ushort_t hh = f2bf_rne(o);
                const ushort_t ll = f2bf_rne(o - bf2f(hh));
                athi[obase + dd] = hh;
                atlo[obase + dd] = ll;
            }
        }
    }
}

// ---------------------------------------------------------------------------
extern "C" void kernel_launch(void* const* d_in, const int* in_sizes, int n_in,
                              void* d_out, int out_size, void* d_ws, size_t ws_size,
                              hipStream_t stream)
{
    const float* x    = (const float*)d_in[0];
    const float* pmk  = (const float*)d_in[1];
    const float* Wq   = (const float*)d_in[2];
    const float* bq   = (const float*)d_in[3];
    const float* Wk   = (const float*)d_in[4];
    const float* bk   = (const float*)d_in[5];
    const float* Wv   = (const float*)d_in[6];
    const float* bv   = (const float*)d_in[7];
    const float* Wo   = (const float*)d_in[8];
    const float* bo   = (const float*)d_in[9];
    const float* posK = (const float*)d_in[10];
    const float* posV = (const float*)d_in[11];
    float* out = (float*)d_out;

    // workspace carve-up
    float* ws = (float*)d_ws;
    float* Qb = ws;                                           // GQ*64 f32
    ushort_t* Kbu = (ushort_t*)(Qb + (size_t)GQ_TOT * DH);    // GQ*64 u16
    ushort_t* Vtu = Kbu + (size_t)GQ_TOT * DH;                // GQ*64 u16 (V^T)
    ushort_t* Qpu = Vtu + (size_t)GQ_TOT * DH;                // GQ*260 u16
    ushort_t* SbandU = Qpu + (size_t)GQ_TOT * QP_STRIDE;      // GQ*256 u16
    ushort_t* athi = SbandU + (size_t)GQ_TOT * 256;           // GQ*64 u16
    ushort_t* atlo = athi + (size_t)GQ_TOT * DH;
    ushort_t* pvTg = atlo + (size_t)GQ_TOT * DH;              // 64*LDPV u16
    float* O1a   = (float*)(pvTg + 64 * LDPV);
    float* O1b   = O1a   + (size_t)GQ_TOT * DH;
    float* lsum2 = O1b   + (size_t)GQ_TOT * DH;
    float* clo2  = lsum2 + 2 * (size_t)GQ_TOT;
    float* chi2  = clo2  + 2 * (size_t)GQ_TOT;

    // bf16 scratch aliased into the Sband region (disjoint lifetimes):
    // phase A (xhi 4.19M + wqkv hi/lo 2x3.15M = 10.5M u16 <= 16.78M region)
    // phase B (Wo hi/lo after post reads bands: 2.1M)
    ushort_t* bb    = SbandU;
    ushort_t* xhi   = bb;
    ushort_t* wqkvh = xhi + 4194304;       // [3072][1024]
    ushort_t* wqkvl = wqkvh + 3145728;
    ushort_t* woh   = bb;
    ushort_t* wol   = woh + 1048576;

    dim3 gb(256);

    split_f32_hi<<<dim3(2048), gb, 0, stream>>>(x, xhi);
    split_transpose3<<<dim3(16, 16, 3), gb, 0, stream>>>(Wq, Wk, Wv, wqkvh, wqkvl);
    prep_pvt<<<dim3(4), gb, 0, stream>>>(posV, pvTg);
    gemm_qkv<<<dim3(64, 48), gb, 0, stream>>>(xhi, wqkvh, wqkvl, bq, bk, bv,
                                              Qb, Kbu, Vtu);
    qp_mfma<<<dim3(1024, 5), gb, 0, stream>>>(Qb, posK, Qpu);
    attn_kernel<<<dim3(2048), gb, 0, stream>>>(Qb, Kbu, Vtu, Qpu, pmk,
                                               SbandU, O1a, O1b, lsum2, clo2, chi2);
    post_mfma<<<dim3(GQ_TOT / 64), gb, 0, stream>>>(SbandU, pvTg, O1a, O1b, lsum2,
                                                    clo2, chi2, posV, athi, atlo);
    split_transpose<<<dim3(16, 16), gb, 0, stream>>>(Wo, woh, wol, 1024, 1024);
    gemm_mfma<<<dim3(64, 16), gb, 0, stream>>>(athi, atlo, woh, wol, bo, out,
                                               4096, 1024, 1024);
}

// Round 14
// 380.683 us; speedup vs baseline: 1.1752x; 1.0089x over previous
//
#include <hip/hip_runtime.h>
#include <math.h>

#define L_SEQ 1024
#define NB 4
#define NH 16
#define DH 64
#define BH_TOT (NB * NH)            // 64
#define GQ_TOT (BH_TOT * L_SEQ)     // 65536
#define NPOS 257                    // 2*128+1
#define QP_STRIDE 260               // padded Qp row stride (u16 elements)
#define LDK 72                      // LDS K-stride (bf16) for attn/gemm tiles
#define LDQP 72                     // stride for QpsP (u16; mult of 8 -> 16B-aligned b128)
#define LDPV 264                    // pvT row stride (u16)

typedef unsigned short ushort_t;
typedef __attribute__((ext_vector_type(8))) short bf16x8;
typedef __attribute__((ext_vector_type(4))) float f32x4;

__device__ inline ushort_t f2bf_rne(float x) {
    unsigned u = __float_as_uint(x);
    unsigned r = u + 0x7FFFu + ((u >> 16) & 1u);
    return (ushort_t)(r >> 16);
}
__device__ inline float bf2f(ushort_t h) {
    return __uint_as_float(((unsigned)h) << 16);
}
__device__ inline uint4 pack8hi(float4 a0, float4 a1) {
    float v[8] = {a0.x, a0.y, a0.z, a0.w, a1.x, a1.y, a1.z, a1.w};
    unsigned hh[4];
    #pragma unroll
    for (int j = 0; j < 4; j++)
        hh[j] = (unsigned)f2bf_rne(v[2*j]) | ((unsigned)f2bf_rne(v[2*j+1]) << 16);
    return (uint4){hh[0], hh[1], hh[2], hh[3]};
}

// ---------------------------------------------------------------------------
// split_f32_hi: A (fp32) -> hi bf16 only.
// ---------------------------------------------------------------------------
__global__ __launch_bounds__(256)
void split_f32_hi(const float* __restrict__ A, ushort_t* __restrict__ hi)
{
    const size_t base = ((size_t)blockIdx.x * 256 + threadIdx.x) * 8;
    *(uint4*)(hi + base) =
        pack8hi(*(const float4*)(A + base), *(const float4*)(A + base + 4));
}

// ---------------------------------------------------------------------------
// split_transpose3: Wq/Wk/Wv (z-indexed) -> contiguous wqkv hi/lo [3072][1024].
// ---------------------------------------------------------------------------
__global__ __launch_bounds__(256)
void split_transpose3(const float* __restrict__ Wq, const float* __restrict__ Wk,
                      const float* __restrict__ Wv, ushort_t* __restrict__ Thi,
                      ushort_t* __restrict__ Tlo)
{
    __shared__ float Ws[64][65];
    const int tid = threadIdx.x;
    const int k0 = blockIdx.x * 64;
    const int n0 = blockIdx.y * 64;
    const int z  = blockIdx.z;
    const float* W = (z == 0) ? Wq : (z == 1) ? Wk : Wv;
    ushort_t* Hh = Thi + (size_t)z * 1048576;
    ushort_t* Ll = Tlo + (size_t)z * 1048576;
    const int r  = tid >> 4;
    const int c4 = (tid & 15) * 4;
    #pragma unroll
    for (int i = 0; i < 4; i++) {
        float4 v = *(const float4*)(W + (size_t)(k0 + r + i*16) * 1024 + n0 + c4);
        Ws[r + i*16][c4+0] = v.x;
        Ws[r + i*16][c4+1] = v.y;
        Ws[r + i*16][c4+2] = v.z;
        Ws[r + i*16][c4+3] = v.w;
    }
    __syncthreads();
    #pragma unroll
    for (int i = 0; i < 4; i++) {
        const int nl = r + i*16;
        ushort_t h[4], l[4];
        #pragma unroll
        for (int j = 0; j < 4; j++) {
            float x = Ws[c4 + j][nl];
            h[j] = f2bf_rne(x);
            l[j] = f2bf_rne(x - bf2f(h[j]));
        }
        size_t off = (size_t)(n0 + nl) * 1024 + k0 + c4;
        uint2 H, L;
        H.x = (unsigned)h[0] | ((unsigned)h[1] << 16);
        H.y = (unsigned)h[2] | ((unsigned)h[3] << 16);
        L.x = (unsigned)l[0] | ((unsigned)l[1] << 16);
        L.y = (unsigned)l[2] | ((unsigned)l[3] << 16);
        *(uint2*)(Hh + off) = H;
        *(uint2*)(Ll + off) = L;
    }
}

// ---------------------------------------------------------------------------
// split_transpose: single-matrix variant (Wo).
// ---------------------------------------------------------------------------
__global__ __launch_bounds__(256)
void split_transpose(const float* __restrict__ W, ushort_t* __restrict__ Thi,
                     ushort_t* __restrict__ Tlo, int Kdim, int Ndim)
{
    __shared__ float Ws[64][65];
    const int tid = threadIdx.x;
    const int k0 = blockIdx.x * 64;
    const int n0 = blockIdx.y * 64;
    const int r  = tid >> 4;
    const int c4 = (tid & 15) * 4;
    #pragma unroll
    for (int i = 0; i < 4; i++) {
        float4 v = *(const float4*)(W + (size_t)(k0 + r + i*16) * Ndim + n0 + c4);
        Ws[r + i*16][c4+0] = v.x;
        Ws[r + i*16][c4+1] = v.y;
        Ws[r + i*16][c4+2] = v.z;
        Ws[r + i*16][c4+3] = v.w;
    }
    __syncthreads();
    #pragma unroll
    for (int i = 0; i < 4; i++) {
        const int nl = r + i*16;
        ushort_t h[4], l[4];
        #pragma unroll
        for (int j = 0; j < 4; j++) {
            float x = Ws[c4 + j][nl];
            h[j] = f2bf_rne(x);
            l[j] = f2bf_rne(x - bf2f(h[j]));
        }
        size_t off = (size_t)(n0 + nl) * Kdim + k0 + c4;
        uint2 H, L;
        H.x = (unsigned)h[0] | ((unsigned)h[1] << 16);
        H.y = (unsigned)h[2] | ((unsigned)h[3] << 16);
        L.x = (unsigned)l[0] | ((unsigned)l[1] << 16);
        L.y = (unsigned)l[2] | ((unsigned)l[3] << 16);
        *(uint2*)(Thi + off) = H;
        *(uint2*)(Tlo + off) = L;
    }
}

// ---------------------------------------------------------------------------
// prep_pvt: posV fp32 [257][64] -> global pvT bf16 [64 d][LDPV r].
// ---------------------------------------------------------------------------
__global__ __launch_bounds__(256)
void prep_pvt(const float* __restrict__ posV, ushort_t* __restrict__ pvTg)
{
    __shared__ float Ws[64][65];
    const int tid = threadIdx.x;
    const int c = blockIdx.x;
    {
        const int r  = tid >> 2;
        const int d0 = (tid & 3) * 16;
        const float* src = posV + (size_t)(c * 64 + r + 1) * 64 + d0;
        #pragma unroll
        for (int i = 0; i < 4; i++) {
            float4 v = *(const float4*)(src + i * 4);
            Ws[r][d0 + i*4 + 0] = v.x;
            Ws[r][d0 + i*4 + 1] = v.y;
            Ws[r][d0 + i*4 + 2] = v.z;
            Ws[r][d0 + i*4 + 3] = v.w;
        }
    }
    __syncthreads();
    {
        const int d  = tid >> 2;
        const int r0 = (tid & 3) * 16;
        #pragma unroll
        for (int k = 0; k < 16; k++)
            pvTg[(size_t)d * LDPV + c * 64 + r0 + k] = f2bf_rne(Ws[r0 + k][d]);
    }
}

// ---------------------------------------------------------------------------
// gemm_qkv: fused Q/K/V projection, one N=3072 launch, 2-term split MFMA.
// ALL outputs bf16 u16 now (R13): fp32 Q precision was never consumed —
// every reader rounded Q to bf16-hi first, so emitting u16 is bit-identical
// and halves Q traffic. nb (block-uniform): 0 -> Q [B,H,L,DH]; 1 -> K same;
// 2 -> V^T [B,H,DH,L].
// ---------------------------------------------------------------------------
__global__ __launch_bounds__(256)
void gemm_qkv(const ushort_t* __restrict__ Ahi,
              const ushort_t* __restrict__ Bhi, const ushort_t* __restrict__ Blo,
              const float* __restrict__ bq, const float* __restrict__ bk,
              const float* __restrict__ bv,
              ushort_t* __restrict__ Qbu, ushort_t* __restrict__ Kbu,
              ushort_t* __restrict__ Vtu)
{
    __shared__ ushort_t As[64 * LDK];
    __shared__ ushort_t Bs[2][64 * LDK];
    const int tid  = threadIdx.x;
    const int m0   = blockIdx.x * 64;
    const int n0   = blockIdx.y * 64;
    const int nb   = n0 >> 10;               // 0=Q, 1=K, 2=V (block-uniform)
    const int wave = tid >> 6, lane = tid & 63;
    const int w0 = wave >> 1, w1 = wave & 1;
    const int lr = lane & 15, lq = lane >> 4;
    const int K = 1024;

    f32x4 acc[2][2];
    #pragma unroll
    for (int i = 0; i < 2; i++)
        #pragma unroll
        for (int j = 0; j < 2; j++)
            acc[i][j] = (f32x4){0.f, 0.f, 0.f, 0.f};

    for (int k0 = 0; k0 < K; k0 += 64) {
        __syncthreads();
        #pragma unroll
        for (int c = 0; c < 2; c++) {
            const int n   = c * 256 + tid;
            const int row = n >> 3;
            const int col = (n & 7) * 8;
            const size_t ga = (size_t)(m0 + row) * K + k0 + col;
            const size_t gb = (size_t)(n0 + row) * K + k0 + col;
            const int la = row * LDK + col;
            *(uint4*)&As[la]    = *(const uint4*)(Ahi + ga);
            *(uint4*)&Bs[0][la] = *(const uint4*)(Bhi + gb);
            *(uint4*)&Bs[1][la] = *(const uint4*)(Blo + gb);
        }
        __syncthreads();
        #pragma unroll
        for (int ks = 0; ks < 2; ks++) {
            bf16x8 ah[2], bh[2], bl[2];
            #pragma unroll
            for (int i = 0; i < 2; i++) {
                const int ar = (w0*32 + i*16 + lr) * LDK + ks*32 + lq*8;
                ah[i] = *(const bf16x8*)&As[ar];
                const int br = (w1*32 + i*16 + lr) * LDK + ks*32 + lq*8;
                bh[i] = *(const bf16x8*)&Bs[0][br];
                bl[i] = *(const bf16x8*)&Bs[1][br];
            }
            #pragma unroll
            for (int i = 0; i < 2; i++)
                #pragma unroll
                for (int j = 0; j < 2; j++) {
                    acc[i][j] = __builtin_amdgcn_mfma_f32_16x16x32_bf16(ah[i], bh[j], acc[i][j], 0, 0, 0);
                    acc[i][j] = __builtin_amdgcn_mfma_f32_16x16x32_bf16(ah[i], bl[j], acc[i][j], 0, 0, 0);
                }
        }
    }

    const float* bp = (nb == 0) ? bq : (nb == 1) ? bk : bv;
    ushort_t* Cout = (nb == 0) ? Qbu : (nb == 1) ? Kbu : Vtu;
    #pragma unroll
    for (int j = 0; j < 2; j++) {
        const int colg = n0 + w1*32 + j*16 + lr;
        const int c1   = colg & 1023;
        const float bcol = bp[c1];
        const int h = c1 >> 6, dd = c1 & 63;
        #pragma unroll
        for (int i = 0; i < 2; i++) {
            #pragma unroll
            for (int r = 0; r < 4; r++) {
                const int m = m0 + w0*32 + i*16 + lq*4 + r;
                const float v = acc[i][j][r] + bcol;
                const int b = m >> 10, lp = m & 1023;
                const size_t off = (nb == 2)
                    ? ((size_t)(b * NH + h) * DH + dd) * L_SEQ + lp
                    : ((size_t)(b * NH + h) * L_SEQ + lp) * DH + dd;
                Cout[off] = f2bf_rne(v);
            }
        }
    }
}

// ---------------------------------------------------------------------------
// gemm_mfma: final output GEMM, 3-term split (output-critical), fp32 out.
// ---------------------------------------------------------------------------
__global__ __launch_bounds__(256)
void gemm_mfma(const ushort_t* __restrict__ Ahi, const ushort_t* __restrict__ Alo,
               const ushort_t* __restrict__ Bhi, const ushort_t* __restrict__ Blo,
               const float* __restrict__ bias, float* __restrict__ C,
               int M, int N, int K)
{
    __shared__ ushort_t As[2][64 * LDK];
    __shared__ ushort_t Bs[2][64 * LDK];
    const int tid  = threadIdx.x;
    const int m0   = blockIdx.x * 64;
    const int n0   = blockIdx.y * 64;
    const int wave = tid >> 6, lane = tid & 63;
    const int w0 = wave >> 1, w1 = wave & 1;
    const int lr = lane & 15, lq = lane >> 4;

    f32x4 acc[2][2];
    #pragma unroll
    for (int i = 0; i < 2; i++)
        #pragma unroll
        for (int j = 0; j < 2; j++)
            acc[i][j] = (f32x4){0.f, 0.f, 0.f, 0.f};

    for (int k0 = 0; k0 < K; k0 += 64) {
        __syncthreads();
        #pragma unroll
        for (int c = 0; c < 2; c++) {
            const int n   = c * 256 + tid;
            const int row = n >> 3;
            const int col = (n & 7) * 8;
            const size_t ga = (size_t)(m0 + row) * K + k0 + col;
            const size_t gb = (size_t)(n0 + row) * K + k0 + col;
            const int la = row * LDK + col;
            *(uint4*)&As[0][la] = *(const uint4*)(Ahi + ga);
            *(uint4*)&As[1][la] = *(const uint4*)(Alo + ga);
            *(uint4*)&Bs[0][la] = *(const uint4*)(Bhi + gb);
            *(uint4*)&Bs[1][la] = *(const uint4*)(Blo + gb);
        }
        __syncthreads();
        #pragma unroll
        for (int ks = 0; ks < 2; ks++) {
            bf16x8 ah[2], al[2], bh[2], bl[2];
            #pragma unroll
            for (int i = 0; i < 2; i++) {
                const int ar = (w0*32 + i*16 + lr) * LDK + ks*32 + lq*8;
                ah[i] = *(const bf16x8*)&As[0][ar];
                al[i] = *(const bf16x8*)&As[1][ar];
                const int br = (w1*32 + i*16 + lr) * LDK + ks*32 + lq*8;
                bh[i] = *(const bf16x8*)&Bs[0][br];
                bl[i] = *(const bf16x8*)&Bs[1][br];
            }
            #pragma unroll
            for (int i = 0; i < 2; i++)
                #pragma unroll
                for (int j = 0; j < 2; j++) {
                    acc[i][j] = __builtin_amdgcn_mfma_f32_16x16x32_bf16(ah[i], bh[j], acc[i][j], 0, 0, 0);
                    acc[i][j] = __builtin_amdgcn_mfma_f32_16x16x32_bf16(ah[i], bl[j], acc[i][j], 0, 0, 0);
                    acc[i][j] = __builtin_amdgcn_mfma_f32_16x16x32_bf16(al[i], bh[j], acc[i][j], 0, 0, 0);
                }
        }
    }

    #pragma unroll
    for (int j = 0; j < 2; j++) {
        const int colg = n0 + w1*32 + j*16 + lr;
        const float bcol = bias[colg];
        #pragma unroll
        for (int i = 0; i < 2; i++) {
            #pragma unroll
            for (int r = 0; r < 4; r++) {
                const int m = m0 + w0*32 + i*16 + lq*4 + r;
                C[(size_t)m * N + colg] = acc[i][j][r] + bcol;
            }
        }
    }
}

// ---------------------------------------------------------------------------
// qp_mfma: Qp[65536 x 257] = Q @ posK^T via MFMA, no LDS. A-frags are now
// direct uint4 loads of bf16 Q (R13). B-frags packed from fp32 posK
// (L2-resident). Grid (1024, 5); col 256 guarded.
// ---------------------------------------------------------------------------
__global__ __launch_bounds__(256)
void qp_mfma(const ushort_t* __restrict__ Qu, const float* __restrict__ posK,
             ushort_t* __restrict__ Qpu)
{
    const int tid = threadIdx.x;
    const size_t m0 = (size_t)blockIdx.x * 64;
    const int n0 = blockIdx.y * 64;
    const int wave = tid >> 6, lane = tid & 63;
    const int wm = (wave >> 1) * 32, wn = (wave & 1) * 32;
    const int lr = lane & 15, lq = lane >> 4;

    bf16x8 af[2][2];
    #pragma unroll
    for (int i = 0; i < 2; i++) {
        const ushort_t* qrow = Qu + (m0 + wm + i*16 + lr) * DH;
        #pragma unroll
        for (int kc = 0; kc < 2; kc++)
            af[i][kc] = *(const bf16x8*)(qrow + kc*32 + lq*8);
    }
    bf16x8 bf[2][2];
    #pragma unroll
    for (int j = 0; j < 2; j++) {
        int n = n0 + wn + j*16 + lr;
        const float* krow = posK + (size_t)(n < 256 ? n : 256) * DH;
        #pragma unroll
        for (int kc = 0; kc < 2; kc++) {
            const float* s = krow + kc*32 + lq*8;
            uint4 u = pack8hi(*(const float4*)s, *(const float4*)(s + 4));
            bf[j][kc] = *(bf16x8*)&u;
        }
    }

    f32x4 acc[2][2];
    #pragma unroll
    for (int i = 0; i < 2; i++)
        #pragma unroll
        for (int j = 0; j < 2; j++)
            acc[i][j] = (f32x4){0.f, 0.f, 0.f, 0.f};
    #pragma unroll
    for (int kc = 0; kc < 2; kc++)
        #pragma unroll
        for (int i = 0; i < 2; i++)
            #pragma unroll
            for (int j = 0; j < 2; j++)
                acc[i][j] = __builtin_amdgcn_mfma_f32_16x16x32_bf16(af[i][kc], bf[j][kc], acc[i][j], 0, 0, 0);

    #pragma unroll
    for (int i = 0; i < 2; i++)
        #pragma unroll
        for (int j = 0; j < 2; j++) {
            const int n = n0 + wn + j*16 + lr;
            if (n < NPOS) {
                #pragma unroll
                for (int r = 0; r < 4; r++) {
                    const size_t m = m0 + wm + i*16 + lq*4 + r;
                    Qpu[m * QP_STRIDE + n] = f2bf_rne(acc[i][j][r]);
                }
            }
        }
}

// ---------------------------------------------------------------------------
// attn v11 = v10 with bf16 Q input (bit-identical: qa was already rounded
// to bf16-hi; now it's a direct uint4 load). Q fetch halves (16.8 MB bf16,
// read by both splits).
// ---------------------------------------------------------------------------
__global__ __launch_bounds__(256)
void attn_kernel(const ushort_t* __restrict__ Qu, const ushort_t* __restrict__ Ku,
                 const ushort_t* __restrict__ Vtu, const ushort_t* __restrict__ Qpu,
                 const float* __restrict__ pm,
                 ushort_t* __restrict__ SbandU,
                 float* __restrict__ O1a, float* __restrict__ O1b,
                 float* __restrict__ lsum2, float* __restrict__ clo2,
                 float* __restrict__ chi2)
{
    __shared__ ushort_t Ks[64 * LDK];
    __shared__ ushort_t Vs[64 * LDK];
    __shared__ ushort_t QpsP[64 * LDQP];
    __shared__ float mk[64];

    const int tid = threadIdx.x;
    const int blk = blockIdx.x;
    const int bh  = blk >> 5;
    const int qb  = (blk >> 1) & 15;
    const int ks  = blk & 1;
    const int b   = bh >> 4;
    const int q0  = qb * 64;
    const size_t gq0 = (size_t)bh * L_SEQ + q0;
    const int wave = tid >> 6, lane = tid & 63;
    const int lr = lane & 15, lq = lane >> 4;
    const int qw = wave * 16;

    const int sr0 = tid >> 3,          sc0 = (tid & 7) * 8;
    const int sr1 = (256 + tid) >> 3,  sc1 = ((256 + tid) & 7) * 8;
    const int qpRowL = qw + (lane >> 2);
    const int qpCol0 = (lane & 3) * 16;

    const ushort_t* Kg  = Ku  + (size_t)bh * (L_SEQ * DH);
    const ushort_t* Vtg = Vtu + (size_t)bh * (DH * L_SEQ);

    bf16x8 qa[2];
    {
        const ushort_t* qrow = Qu + (gq0 + qw + lr) * DH;
        #pragma unroll
        for (int kc = 0; kc < 2; kc++)
            qa[kc] = *(const bf16x8*)(qrow + kc * 32 + lq * 8);
    }

    if (ks == 0 && tid < 64) {
        const int q = q0 + tid;
        ushort_t* bandRow = SbandU + (gq0 + tid) * 256;
        for (int j = 0; j < 127 - q; j++)    bandRow[j] = 0;
        for (int j = 254; j > 1150 - q; j--) bandRow[j] = 0;
        bandRow[255] = 0;
    }

    f32x4 Oacc[4];
    #pragma unroll
    for (int j = 0; j < 4; j++) Oacc[j] = (f32x4){0.f, 0.f, 0.f, 0.f};
    float lpart[4] = {}, clpart[4] = {}, chpart[4] = {};

    uint4 kva0, kva1, kvb0, kvb1;
    ushort_t qpr[16];
    float mkr = 0.f;
    {
        const int k0 = ks * 512;
        kva0 = *(const uint4*)(Kg + (size_t)(k0 + sr0) * DH + sc0);
        kva1 = *(const uint4*)(Kg + (size_t)(k0 + sr1) * DH + sc1);
        kvb0 = *(const uint4*)(Vtg + (size_t)sr0 * L_SEQ + k0 + sc0);
        kvb1 = *(const uint4*)(Vtg + (size_t)sr1 * L_SEQ + k0 + sc1);
        const int qg = q0 + qpRowL;
        #pragma unroll
        for (int c = 0; c < 16; c++) {
            int rel = k0 + qpCol0 + c - qg;
            rel = rel < -128 ? -128 : (rel > 128 ? 128 : rel);
            qpr[c] = Qpu[(gq0 + qpRowL) * QP_STRIDE + rel + 128];
        }
        if (tid < 64) mkr = pm[b * L_SEQ + k0 + tid];
    }

    for (int t = 0; t < 8; t++) {
        const int k0 = (ks * 8 + t) * 64;
        __syncthreads();   // (a)

        *(uint4*)&Ks[sr0 * LDK + sc0] = kva0;
        *(uint4*)&Ks[sr1 * LDK + sc1] = kva1;
        *(uint4*)&Vs[sr0 * LDK + sc0] = kvb0;
        *(uint4*)&Vs[sr1 * LDK + sc1] = kvb1;
        {
            ushort_t* dst = &QpsP[qpRowL * LDQP + qpCol0];
            #pragma unroll
            for (int c = 0; c < 8; c++)
                ((unsigned*)dst)[c] = (unsigned)qpr[2*c] | ((unsigned)qpr[2*c+1] << 16);
        }
        if (tid < 64) mk[tid] = mkr;
        __syncthreads();   // (b)

        if (t < 7) {
            const int k0n = k0 + 64;
            kva0 = *(const uint4*)(Kg + (size_t)(k0n + sr0) * DH + sc0);
            kva1 = *(const uint4*)(Kg + (size_t)(k0n + sr1) * DH + sc1);
            kvb0 = *(const uint4*)(Vtg + (size_t)sr0 * L_SEQ + k0n + sc0);
            kvb1 = *(const uint4*)(Vtg + (size_t)sr1 * L_SEQ + k0n + sc1);
            const int qg = q0 + qpRowL;
            #pragma unroll
            for (int c = 0; c < 16; c++) {
                int rel = k0n + qpCol0 + c - qg;
                rel = rel < -128 ? -128 : (rel > 128 ? 128 : rel);
                qpr[c] = Qpu[(gq0 + qpRowL) * QP_STRIDE + rel + 128];
            }
            if (tid < 64) mkr = pm[b * L_SEQ + k0n + tid];
        }

        f32x4 Sacc[4];
        #pragma unroll
        for (int j = 0; j < 4; j++) Sacc[j] = (f32x4){0.f, 0.f, 0.f, 0.f};
        #pragma unroll
        for (int kc = 0; kc < 2; kc++) {
            #pragma unroll
            for (int j = 0; j < 4; j++) {
                bf16x8 kb = *(const bf16x8*)&Ks[(j*16 + lr) * LDK + kc*32 + lq*8];
                Sacc[j] = __builtin_amdgcn_mfma_f32_16x16x32_bf16(qa[kc], kb, Sacc[j], 0, 0, 0);
            }
        }

        ushort_t pb[4][4];
        #pragma unroll
        for (int r = 0; r < 4; r++) {
            const int ql = qw + lq*4 + r;
            const int q  = q0 + ql;
            const size_t gq = gq0 + ql;
            ushort_t* bandRow = SbandU + gq * 256 + 127;
            #pragma unroll
            for (int j = 0; j < 4; j++) {
                const int kl = j*16 + lr;
                const int k  = k0 + kl;
                const int rel = k - q;
                float s = (Sacc[j][r] + bf2f(QpsP[ql * LDQP + kl])) * 0.125f;
                s *= mk[kl];
                const float p = __expf(s);
                lpart[r] += p;
                const ushort_t ph = f2bf_rne(p);
                if (rel <= -128)      clpart[r] += p;
                else if (rel >= 128)  chpart[r] += p;
                else                  bandRow[rel] = ph;
                pb[j][r] = ph;
            }
        }

        #pragma unroll
        for (int r = 0; r < 4; r++)
            #pragma unroll
            for (int j = 0; j < 4; j++)
                QpsP[(qw + lq*4 + r) * LDQP + j*16 + lr] = pb[j][r];

        #pragma unroll
        for (int kc = 0; kc < 2; kc++) {
            bf16x8 pa = *(const bf16x8*)&QpsP[(qw + lr) * LDQP + kc*32 + lq*8];
            #pragma unroll
            for (int j = 0; j < 4; j++) {
                bf16x8 vb = *(const bf16x8*)&Vs[(j*16 + lr) * LDK + kc*32 + lq*8];
                Oacc[j] = __builtin_amdgcn_mfma_f32_16x16x32_bf16(pa, vb, Oacc[j], 0, 0, 0);
            }
        }
    }

    #pragma unroll
    for (int off = 1; off < 16; off <<= 1) {
        #pragma unroll
        for (int r = 0; r < 4; r++) {
            lpart[r]  += __shfl_xor(lpart[r],  off, 64);
            clpart[r] += __shfl_xor(clpart[r], off, 64);
            chpart[r] += __shfl_xor(chpart[r], off, 64);
        }
    }
    if (lr == 0) {
        #pragma unroll
        for (int r = 0; r < 4; r++) {
            const size_t o = (size_t)ks * GQ_TOT + gq0 + qw + lq*4 + r;
            lsum2[o] = lpart[r];
            clo2[o]  = clpart[r];
            chi2[o]  = chpart[r];
        }
    }

    float* O1o = ks ? O1b : O1a;
    #pragma unroll
    for (int j = 0; j < 4; j++)
        #pragma unroll
        for (int r = 0; r < 4; r++)
            O1o[(gq0 + qw + lq*4 + r) * DH + j*16 + lr] = Oacc[j][r];
}

// ---------------------------------------------------------------------------
// post_mfma (R10-proven): O2 = band @ posV^T via MFMA; fused epilogue emits
// athi/atlo bf16 split directly.
// ---------------------------------------------------------------------------
__global__ __launch_bounds__(256)
void post_mfma(const ushort_t* __restrict__ SbandU, const ushort_t* __restrict__ pvTg,
               const float* __restrict__ O1a, const float* __restrict__ O1b,
               const float* __restrict__ lsum2, const float* __restrict__ clo2,
               const float* __restrict__ chi2, const float* __restrict__ posV,
               ushort_t* __restrict__ athi, ushort_t* __restrict__ atlo)
{
    __shared__ ushort_t pvT[64 * LDPV];
    const int tid = threadIdx.x;
    const size_t q0 = (size_t)blockIdx.x * 64;
    const int wave = tid >> 6, lane = tid & 63;
    const int w0 = wave >> 1, w1 = wave & 1;
    const int lr = lane & 15, lq = lane >> 4;

    {
        const unsigned* src = (const unsigned*)pvTg;
        unsigned* dst = (unsigned*)pvT;
        for (int i = tid; i < 64 * LDPV / 2; i += 256) dst[i] = src[i];
    }
    __syncthreads();

    f32x4 acc[2][2];
    #pragma unroll
    for (int i = 0; i < 2; i++)
        #pragma unroll
        for (int j = 0; j < 2; j++)
            acc[i][j] = (f32x4){0.f, 0.f, 0.f, 0.f};

    const ushort_t* bandB = SbandU + q0 * 256;
    #pragma unroll
    for (int kc = 0; kc < 8; kc++) {
        bf16x8 a[2], bv[2];
        #pragma unroll
        for (int i = 0; i < 2; i++) {
            a[i]  = *(const bf16x8*)&bandB[(size_t)(w0*32 + i*16 + lr) * 256 + kc*32 + lq*8];
            bv[i] = *(const bf16x8*)&pvT[(w1*32 + i*16 + lr) * LDPV + kc*32 + lq*8];
        }
        #pragma unroll
        for (int i = 0; i < 2; i++)
            #pragma unroll
            for (int j = 0; j < 2; j++)
                acc[i][j] = __builtin_amdgcn_mfma_f32_16x16x32_bf16(a[i], bv[j], acc[i][j], 0, 0, 0);
    }

    #pragma unroll
    for (int i = 0; i < 2; i++) {
        #pragma unroll
        for (int r = 0; r < 4; r++) {
            const int ql = w0*32 + i*16 + lq*4 + r;
            const size_t gq = q0 + ql;
            const float li = lsum2[gq] + lsum2[GQ_TOT + gq];
            const float cl = clo2[gq]  + clo2[GQ_TOT + gq];
            const float ch = chi2[gq]  + chi2[GQ_TOT + gq];
            const float inv = 1.0f / li;
            const int b  = (int)(gq >> 14);
            const int h  = (int)((gq >> 10) & 15);
            const int lp = (int)(gq & 1023);
            const size_t obase = ((size_t)(b * L_SEQ + lp) * 1024) + h * 64;
            #pragma unroll
            for (int j = 0; j < 2; j++) {
                const int dd = w1*32 + j*16 + lr;
                float o = O1a[gq * DH + dd] + O1b[gq * DH + dd] + acc[i][j][r]
                        + cl * posV[dd] + ch * posV[256 * 64 + dd];
                o *= inv;
                const ushort_t hh = f2bf_rne(o);
                const ushort_t ll = f2bf_rne(o - bf2f(hh));
                athi[obase + dd] = hh;
                atlo[obase + dd] = ll;
            }
        }
    }
}

// ---------------------------------------------------------------------------
extern "C" void kernel_launch(void* const* d_in, const int* in_sizes, int n_in,
                              void* d_out, int out_size, void* d_ws, size_t ws_size,
                              hipStream_t stream)
{
    const float* x    = (const float*)d_in[0];
    const float* pmk  = (const float*)d_in[1];
    const float* Wq   = (const float*)d_in[2];
    const float* bq   = (const float*)d_in[3];
    const float* Wk   = (const float*)d_in[4];
    const float* bk   = (const float*)d_in[5];
    const float* Wv   = (const float*)d_in[6];
    const float* bv   = (const float*)d_in[7];
    const float* Wo   = (const float*)d_in[8];
    const float* bo   = (const float*)d_in[9];
    const float* posK = (const float*)d_in[10];
    const float* posV = (const float*)d_in[11];
    float* out = (float*)d_out;

    // workspace carve-up (u16 first, then f32)
    ushort_t* u = (ushort_t*)d_ws;
    ushort_t* Qbu    = u;                                 // GQ*64 u16 (bf16 Q)
    ushort_t* Kbu    = Qbu + (size_t)GQ_TOT * DH;
    ushort_t* Vtu    = Kbu + (size_t)GQ_TOT * DH;         // V^T
    ushort_t* Qpu    = Vtu + (size_t)GQ_TOT * DH;         // GQ*260
    ushort_t* SbandU = Qpu + (size_t)GQ_TOT * QP_STRIDE;  // GQ*256
    ushort_t* athi   = SbandU + (size_t)GQ_TOT * 256;
    ushort_t* atlo   = athi + (size_t)GQ_TOT * DH;
    ushort_t* pvTg   = atlo + (size_t)GQ_TOT * DH;
    float* O1a   = (float*)(pvTg + 64 * LDPV + 64);       // pad to 4B align
    float* O1b   = O1a   + (size_t)GQ_TOT * DH;
    float* lsum2 = O1b   + (size_t)GQ_TOT * DH;
    float* clo2  = lsum2 + 2 * (size_t)GQ_TOT;
    float* chi2  = clo2  + 2 * (size_t)GQ_TOT;

    // bf16 scratch aliased into the Sband region (disjoint lifetimes):
    // phase A (xhi 4.19M + wqkv hi/lo 2x3.15M = 10.5M u16 <= 16.78M region)
    // phase B (Wo hi/lo after post reads bands: 2.1M)
    ushort_t* bb    = SbandU;
    ushort_t* xhi   = bb;
    ushort_t* wqkvh = xhi + 4194304;       // [3072][1024]
    ushort_t* wqkvl = wqkvh + 3145728;
    ushort_t* woh   = bb;
    ushort_t* wol   = woh + 1048576;

    dim3 gb(256);

    split_f32_hi<<<dim3(2048), gb, 0, stream>>>(x, xhi);
    split_transpose3<<<dim3(16, 16, 3), gb, 0, stream>>>(Wq, Wk, Wv, wqkvh, wqkvl);
    prep_pvt<<<dim3(4), gb, 0, stream>>>(posV, pvTg);
    gemm_qkv<<<dim3(64, 48), gb, 0, stream>>>(xhi, wqkvh, wqkvl, bq, bk, bv,
                                              Qbu, Kbu, Vtu);
    qp_mfma<<<dim3(1024, 5), gb, 0, stream>>>(Qbu, posK, Qpu);
    attn_kernel<<<dim3(2048), gb, 0, stream>>>(Qbu, Kbu, Vtu, Qpu, pmk,
                                               SbandU, O1a, O1b, lsum2, clo2, chi2);
    post_mfma<<<dim3(GQ_TOT / 64), gb, 0, stream>>>(SbandU, pvTg, O1a, O1b, lsum2,
                                                    clo2, chi2, posV, athi, atlo);
    split_transpose<<<dim3(16, 16), gb, 0, stream>>>(Wo, woh, wol, 1024, 1024);
    gemm_mfma<<<dim3(64, 16), gb, 0, stream>>>(athi, atlo, woh, wol, bo, out,
                                               4096, 1024, 1024);
}

// Round 15
// 359.917 us; speedup vs baseline: 1.2430x; 1.0577x over previous
//
#include <hip/hip_runtime.h>
#include <math.h>

#define L_SEQ 1024
#define NB 4
#define NH 16
#define DH 64
#define BH_TOT (NB * NH)            // 64
#define GQ_TOT (BH_TOT * L_SEQ)     // 65536
#define NPOS 257                    // 2*128+1
#define QP_STRIDE 260               // padded Qp row stride (u16 elements)
#define LDK 72                      // LDS K-stride (bf16) for attn/64-gemm tiles
#define LDQP 72                     // stride for QpsP (u16)
#define LDPV 264                    // pvT row stride (u16)
#define LDK32 40                    // LDS stride for gemm128 (BK=32 + pad; 2-way reads, free)

typedef unsigned short ushort_t;
typedef __attribute__((ext_vector_type(8))) short bf16x8;
typedef __attribute__((ext_vector_type(4))) float f32x4;

__device__ inline ushort_t f2bf_rne(float x) {
    unsigned u = __float_as_uint(x);
    unsigned r = u + 0x7FFFu + ((u >> 16) & 1u);
    return (ushort_t)(r >> 16);
}
__device__ inline float bf2f(ushort_t h) {
    return __uint_as_float(((unsigned)h) << 16);
}
__device__ inline uint4 pack8hi(float4 a0, float4 a1) {
    float v[8] = {a0.x, a0.y, a0.z, a0.w, a1.x, a1.y, a1.z, a1.w};
    unsigned hh[4];
    #pragma unroll
    for (int j = 0; j < 4; j++)
        hh[j] = (unsigned)f2bf_rne(v[2*j]) | ((unsigned)f2bf_rne(v[2*j+1]) << 16);
    return (uint4){hh[0], hh[1], hh[2], hh[3]};
}

// ---------------------------------------------------------------------------
// split_f32_hi: A (fp32) -> hi bf16 only.
// ---------------------------------------------------------------------------
__global__ __launch_bounds__(256)
void split_f32_hi(const float* __restrict__ A, ushort_t* __restrict__ hi)
{
    const size_t base = ((size_t)blockIdx.x * 256 + threadIdx.x) * 8;
    *(uint4*)(hi + base) =
        pack8hi(*(const float4*)(A + base), *(const float4*)(A + base + 4));
}

// ---------------------------------------------------------------------------
// split_transpose3: Wq/Wk/Wv (z-indexed) -> contiguous wqkv hi/lo [3072][1024].
// ---------------------------------------------------------------------------
__global__ __launch_bounds__(256)
void split_transpose3(const float* __restrict__ Wq, const float* __restrict__ Wk,
                      const float* __restrict__ Wv, ushort_t* __restrict__ Thi,
                      ushort_t* __restrict__ Tlo)
{
    __shared__ float Ws[64][65];
    const int tid = threadIdx.x;
    const int k0 = blockIdx.x * 64;
    const int n0 = blockIdx.y * 64;
    const int z  = blockIdx.z;
    const float* W = (z == 0) ? Wq : (z == 1) ? Wk : Wv;
    ushort_t* Hh = Thi + (size_t)z * 1048576;
    ushort_t* Ll = Tlo + (size_t)z * 1048576;
    const int r  = tid >> 4;
    const int c4 = (tid & 15) * 4;
    #pragma unroll
    for (int i = 0; i < 4; i++) {
        float4 v = *(const float4*)(W + (size_t)(k0 + r + i*16) * 1024 + n0 + c4);
        Ws[r + i*16][c4+0] = v.x;
        Ws[r + i*16][c4+1] = v.y;
        Ws[r + i*16][c4+2] = v.z;
        Ws[r + i*16][c4+3] = v.w;
    }
    __syncthreads();
    #pragma unroll
    for (int i = 0; i < 4; i++) {
        const int nl = r + i*16;
        ushort_t h[4], l[4];
        #pragma unroll
        for (int j = 0; j < 4; j++) {
            float x = Ws[c4 + j][nl];
            h[j] = f2bf_rne(x);
            l[j] = f2bf_rne(x - bf2f(h[j]));
        }
        size_t off = (size_t)(n0 + nl) * 1024 + k0 + c4;
        uint2 H, L;
        H.x = (unsigned)h[0] | ((unsigned)h[1] << 16);
        H.y = (unsigned)h[2] | ((unsigned)h[3] << 16);
        L.x = (unsigned)l[0] | ((unsigned)l[1] << 16);
        L.y = (unsigned)l[2] | ((unsigned)l[3] << 16);
        *(uint2*)(Hh + off) = H;
        *(uint2*)(Ll + off) = L;
    }
}

// ---------------------------------------------------------------------------
// split_transpose: single-matrix variant (Wo).
// ---------------------------------------------------------------------------
__global__ __launch_bounds__(256)
void split_transpose(const float* __restrict__ W, ushort_t* __restrict__ Thi,
                     ushort_t* __restrict__ Tlo, int Kdim, int Ndim)
{
    __shared__ float Ws[64][65];
    const int tid = threadIdx.x;
    const int k0 = blockIdx.x * 64;
    const int n0 = blockIdx.y * 64;
    const int r  = tid >> 4;
    const int c4 = (tid & 15) * 4;
    #pragma unroll
    for (int i = 0; i < 4; i++) {
        float4 v = *(const float4*)(W + (size_t)(k0 + r + i*16) * Ndim + n0 + c4);
        Ws[r + i*16][c4+0] = v.x;
        Ws[r + i*16][c4+1] = v.y;
        Ws[r + i*16][c4+2] = v.z;
        Ws[r + i*16][c4+3] = v.w;
    }
    __syncthreads();
    #pragma unroll
    for (int i = 0; i < 4; i++) {
        const int nl = r + i*16;
        ushort_t h[4], l[4];
        #pragma unroll
        for (int j = 0; j < 4; j++) {
            float x = Ws[c4 + j][nl];
            h[j] = f2bf_rne(x);
            l[j] = f2bf_rne(x - bf2f(h[j]));
        }
        size_t off = (size_t)(n0 + nl) * Kdim + k0 + c4;
        uint2 H, L;
        H.x = (unsigned)h[0] | ((unsigned)h[1] << 16);
        H.y = (unsigned)h[2] | ((unsigned)h[3] << 16);
        L.x = (unsigned)l[0] | ((unsigned)l[1] << 16);
        L.y = (unsigned)l[2] | ((unsigned)l[3] << 16);
        *(uint2*)(Thi + off) = H;
        *(uint2*)(Tlo + off) = L;
    }
}

// ---------------------------------------------------------------------------
// prep_pvt: posV fp32 [257][64] -> global pvT bf16 [64 d][LDPV r].
// ---------------------------------------------------------------------------
__global__ __launch_bounds__(256)
void prep_pvt(const float* __restrict__ posV, ushort_t* __restrict__ pvTg)
{
    __shared__ float Ws[64][65];
    const int tid = threadIdx.x;
    const int c = blockIdx.x;
    {
        const int r  = tid >> 2;
        const int d0 = (tid & 3) * 16;
        const float* src = posV + (size_t)(c * 64 + r + 1) * 64 + d0;
        #pragma unroll
        for (int i = 0; i < 4; i++) {
            float4 v = *(const float4*)(src + i * 4);
            Ws[r][d0 + i*4 + 0] = v.x;
            Ws[r][d0 + i*4 + 1] = v.y;
            Ws[r][d0 + i*4 + 2] = v.z;
            Ws[r][d0 + i*4 + 3] = v.w;
        }
    }
    __syncthreads();
    {
        const int d  = tid >> 2;
        const int r0 = (tid & 3) * 16;
        #pragma unroll
        for (int k = 0; k < 16; k++)
            pvTg[(size_t)d * LDPV + c * 64 + r0 + k] = f2bf_rne(Ws[r0 + k][d]);
    }
}

// ---------------------------------------------------------------------------
// gemm_qkv128: fused QKV projection, 128x128 tile, BK=32, register prefetch.
// 2-term split MFMA (Ahi.Bhi + Ahi.Blo). Per wave-ktile: 32 MFMA : 12 ds_read
// (64-tile was 16:12); B tiles serve 128 A-rows (traffic halved). LDS 30 KB
// -> 2 blocks/CU. Grid (32, 24) = 768 blocks.
// nb = n0>>10 (block-uniform, 128 | 1024): 0 -> Q bf16 [B,H,L,DH];
// 1 -> K same; 2 -> V^T [B,H,DH,L].
// ---------------------------------------------------------------------------
__global__ __launch_bounds__(256)
void gemm_qkv128(const ushort_t* __restrict__ Ahi,
                 const ushort_t* __restrict__ Bhi, const ushort_t* __restrict__ Blo,
                 const float* __restrict__ bq, const float* __restrict__ bk,
                 const float* __restrict__ bv,
                 ushort_t* __restrict__ Qbu, ushort_t* __restrict__ Kbu,
                 ushort_t* __restrict__ Vtu)
{
    __shared__ ushort_t As[128 * LDK32];      // A-hi
    __shared__ ushort_t Bs[2][128 * LDK32];   // B hi/lo
    const int tid  = threadIdx.x;
    const int m0   = blockIdx.x * 128;
    const int n0   = blockIdx.y * 128;
    const int nb   = n0 >> 10;
    const int wave = tid >> 6, lane = tid & 63;
    const int wr = wave >> 1, wc = wave & 1;
    const int lr = lane & 15, lq = lane >> 4;
    const int K = 1024;

    // staging slots: 512 uint4 per tile; 2 per thread
    const int r0 = tid >> 1,        c0 = (tid & 1) * 16;   // rows 0..127, col 0/16
    // slot geometry: thread covers (row=tid>>1, cols c0..c0+15) as 2x uint4?
    // simpler: slot s = tid and s = 256+tid with row=s>>2, c8=(s&3)*8
    const int sA0 = tid,       rA0 = sA0 >> 2, cA0 = (sA0 & 3) * 8;
    const int sA1 = 256 + tid, rA1 = sA1 >> 2, cA1 = (sA1 & 3) * 8;
    (void)r0; (void)c0;

    f32x4 acc[4][4];
    #pragma unroll
    for (int i = 0; i < 4; i++)
        #pragma unroll
        for (int j = 0; j < 4; j++)
            acc[i][j] = (f32x4){0.f, 0.f, 0.f, 0.f};

    uint4 pa0, pa1, pbh0, pbh1, pbl0, pbl1;
    {
        const size_t a0 = (size_t)(m0 + rA0) * K + cA0, a1 = (size_t)(m0 + rA1) * K + cA1;
        const size_t b0 = (size_t)(n0 + rA0) * K + cA0, b1 = (size_t)(n0 + rA1) * K + cA1;
        pa0  = *(const uint4*)(Ahi + a0); pa1  = *(const uint4*)(Ahi + a1);
        pbh0 = *(const uint4*)(Bhi + b0); pbh1 = *(const uint4*)(Bhi + b1);
        pbl0 = *(const uint4*)(Blo + b0); pbl1 = *(const uint4*)(Blo + b1);
    }

    for (int it = 0; it < 32; it++) {
        __syncthreads();
        *(uint4*)&As[rA0 * LDK32 + cA0]    = pa0;
        *(uint4*)&As[rA1 * LDK32 + cA1]    = pa1;
        *(uint4*)&Bs[0][rA0 * LDK32 + cA0] = pbh0;
        *(uint4*)&Bs[0][rA1 * LDK32 + cA1] = pbh1;
        *(uint4*)&Bs[1][rA0 * LDK32 + cA0] = pbl0;
        *(uint4*)&Bs[1][rA1 * LDK32 + cA1] = pbl1;
        __syncthreads();
        if (it < 31) {
            const int k0 = (it + 1) * 32;
            const size_t a0 = (size_t)(m0 + rA0) * K + k0 + cA0, a1 = (size_t)(m0 + rA1) * K + k0 + cA1;
            const size_t b0 = (size_t)(n0 + rA0) * K + k0 + cA0, b1 = (size_t)(n0 + rA1) * K + k0 + cA1;
            pa0  = *(const uint4*)(Ahi + a0); pa1  = *(const uint4*)(Ahi + a1);
            pbh0 = *(const uint4*)(Bhi + b0); pbh1 = *(const uint4*)(Bhi + b1);
            pbl0 = *(const uint4*)(Blo + b0); pbl1 = *(const uint4*)(Blo + b1);
        }

        bf16x8 ah[4], bh[4], bl[4];
        #pragma unroll
        for (int i = 0; i < 4; i++) {
            ah[i] = *(const bf16x8*)&As[(wr*64 + i*16 + lr) * LDK32 + lq*8];
            const int br = (wc*64 + i*16 + lr) * LDK32 + lq*8;
            bh[i] = *(const bf16x8*)&Bs[0][br];
            bl[i] = *(const bf16x8*)&Bs[1][br];
        }
        #pragma unroll
        for (int i = 0; i < 4; i++)
            #pragma unroll
            for (int j = 0; j < 4; j++) {
                acc[i][j] = __builtin_amdgcn_mfma_f32_16x16x32_bf16(ah[i], bh[j], acc[i][j], 0, 0, 0);
                acc[i][j] = __builtin_amdgcn_mfma_f32_16x16x32_bf16(ah[i], bl[j], acc[i][j], 0, 0, 0);
            }
    }

    const float* bp = (nb == 0) ? bq : (nb == 1) ? bk : bv;
    ushort_t* Cout = (nb == 0) ? Qbu : (nb == 1) ? Kbu : Vtu;
    #pragma unroll
    for (int j = 0; j < 4; j++) {
        const int colg = n0 + wc*64 + j*16 + lr;
        const int c1   = colg & 1023;
        const float bcol = bp[c1];
        const int h = c1 >> 6, dd = c1 & 63;
        #pragma unroll
        for (int i = 0; i < 4; i++) {
            #pragma unroll
            for (int r = 0; r < 4; r++) {
                const int m = m0 + wr*64 + i*16 + lq*4 + r;
                const float v = acc[i][j][r] + bcol;
                const int b = m >> 10, lp = m & 1023;
                const size_t off = (nb == 2)
                    ? ((size_t)(b * NH + h) * DH + dd) * L_SEQ + lp
                    : ((size_t)(b * NH + h) * L_SEQ + lp) * DH + dd;
                Cout[off] = f2bf_rne(v);
            }
        }
    }
}

// ---------------------------------------------------------------------------
// gemm_mfma: final output GEMM, 3-term split (output-critical), fp32 out.
// ---------------------------------------------------------------------------
__global__ __launch_bounds__(256)
void gemm_mfma(const ushort_t* __restrict__ Ahi, const ushort_t* __restrict__ Alo,
               const ushort_t* __restrict__ Bhi, const ushort_t* __restrict__ Blo,
               const float* __restrict__ bias, float* __restrict__ C,
               int M, int N, int K)
{
    __shared__ ushort_t As[2][64 * LDK];
    __shared__ ushort_t Bs[2][64 * LDK];
    const int tid  = threadIdx.x;
    const int m0   = blockIdx.x * 64;
    const int n0   = blockIdx.y * 64;
    const int wave = tid >> 6, lane = tid & 63;
    const int w0 = wave >> 1, w1 = wave & 1;
    const int lr = lane & 15, lq = lane >> 4;

    f32x4 acc[2][2];
    #pragma unroll
    for (int i = 0; i < 2; i++)
        #pragma unroll
        for (int j = 0; j < 2; j++)
            acc[i][j] = (f32x4){0.f, 0.f, 0.f, 0.f};

    for (int k0 = 0; k0 < K; k0 += 64) {
        __syncthreads();
        #pragma unroll
        for (int c = 0; c < 2; c++) {
            const int n   = c * 256 + tid;
            const int row = n >> 3;
            const int col = (n & 7) * 8;
            const size_t ga = (size_t)(m0 + row) * K + k0 + col;
            const size_t gb = (size_t)(n0 + row) * K + k0 + col;
            const int la = row * LDK + col;
            *(uint4*)&As[0][la] = *(const uint4*)(Ahi + ga);
            *(uint4*)&As[1][la] = *(const uint4*)(Alo + ga);
            *(uint4*)&Bs[0][la] = *(const uint4*)(Bhi + gb);
            *(uint4*)&Bs[1][la] = *(const uint4*)(Blo + gb);
        }
        __syncthreads();
        #pragma unroll
        for (int ks = 0; ks < 2; ks++) {
            bf16x8 ah[2], al[2], bh[2], bl[2];
            #pragma unroll
            for (int i = 0; i < 2; i++) {
                const int ar = (w0*32 + i*16 + lr) * LDK + ks*32 + lq*8;
                ah[i] = *(const bf16x8*)&As[0][ar];
                al[i] = *(const bf16x8*)&As[1][ar];
                const int br = (w1*32 + i*16 + lr) * LDK + ks*32 + lq*8;
                bh[i] = *(const bf16x8*)&Bs[0][br];
                bl[i] = *(const bf16x8*)&Bs[1][br];
            }
            #pragma unroll
            for (int i = 0; i < 2; i++)
                #pragma unroll
                for (int j = 0; j < 2; j++) {
                    acc[i][j] = __builtin_amdgcn_mfma_f32_16x16x32_bf16(ah[i], bh[j], acc[i][j], 0, 0, 0);
                    acc[i][j] = __builtin_amdgcn_mfma_f32_16x16x32_bf16(ah[i], bl[j], acc[i][j], 0, 0, 0);
                    acc[i][j] = __builtin_amdgcn_mfma_f32_16x16x32_bf16(al[i], bh[j], acc[i][j], 0, 0, 0);
                }
        }
    }

    #pragma unroll
    for (int j = 0; j < 2; j++) {
        const int colg = n0 + w1*32 + j*16 + lr;
        const float bcol = bias[colg];
        #pragma unroll
        for (int i = 0; i < 2; i++) {
            #pragma unroll
            for (int r = 0; r < 4; r++) {
                const int m = m0 + w0*32 + i*16 + lq*4 + r;
                C[(size_t)m * N + colg] = acc[i][j][r] + bcol;
            }
        }
    }
}

// ---------------------------------------------------------------------------
// qp_mfma: Qp[65536 x 257] = Q @ posK^T via MFMA, no LDS.
// ---------------------------------------------------------------------------
__global__ __launch_bounds__(256)
void qp_mfma(const ushort_t* __restrict__ Qu, const float* __restrict__ posK,
             ushort_t* __restrict__ Qpu)
{
    const int tid = threadIdx.x;
    const size_t m0 = (size_t)blockIdx.x * 64;
    const int n0 = blockIdx.y * 64;
    const int wave = tid >> 6, lane = tid & 63;
    const int wm = (wave >> 1) * 32, wn = (wave & 1) * 32;
    const int lr = lane & 15, lq = lane >> 4;

    bf16x8 af[2][2];
    #pragma unroll
    for (int i = 0; i < 2; i++) {
        const ushort_t* qrow = Qu + (m0 + wm + i*16 + lr) * DH;
        #pragma unroll
        for (int kc = 0; kc < 2; kc++)
            af[i][kc] = *(const bf16x8*)(qrow + kc*32 + lq*8);
    }
    bf16x8 bf[2][2];
    #pragma unroll
    for (int j = 0; j < 2; j++) {
        int n = n0 + wn + j*16 + lr;
        const float* krow = posK + (size_t)(n < 256 ? n : 256) * DH;
        #pragma unroll
        for (int kc = 0; kc < 2; kc++) {
            const float* s = krow + kc*32 + lq*8;
            uint4 u = pack8hi(*(const float4*)s, *(const float4*)(s + 4));
            bf[j][kc] = *(bf16x8*)&u;
        }
    }

    f32x4 acc[2][2];
    #pragma unroll
    for (int i = 0; i < 2; i++)
        #pragma unroll
        for (int j = 0; j < 2; j++)
            acc[i][j] = (f32x4){0.f, 0.f, 0.f, 0.f};
    #pragma unroll
    for (int kc = 0; kc < 2; kc++)
        #pragma unroll
        for (int i = 0; i < 2; i++)
            #pragma unroll
            for (int j = 0; j < 2; j++)
                acc[i][j] = __builtin_amdgcn_mfma_f32_16x16x32_bf16(af[i][kc], bf[j][kc], acc[i][j], 0, 0, 0);

    #pragma unroll
    for (int i = 0; i < 2; i++)
        #pragma unroll
        for (int j = 0; j < 2; j++) {
            const int n = n0 + wn + j*16 + lr;
            if (n < NPOS) {
                #pragma unroll
                for (int r = 0; r < 4; r++) {
                    const size_t m = m0 + wm + i*16 + lq*4 + r;
                    Qpu[m * QP_STRIDE + n] = f2bf_rne(acc[i][j][r]);
                }
            }
        }
}

// ---------------------------------------------------------------------------
// attn v12 = v11 with bf16 O1 partials (halves O1 write traffic; error
// ~7e-5 on attn after /l — in budget).
// ---------------------------------------------------------------------------
__global__ __launch_bounds__(256)
void attn_kernel(const ushort_t* __restrict__ Qu, const ushort_t* __restrict__ Ku,
                 const ushort_t* __restrict__ Vtu, const ushort_t* __restrict__ Qpu,
                 const float* __restrict__ pm,
                 ushort_t* __restrict__ SbandU,
                 ushort_t* __restrict__ O1a, ushort_t* __restrict__ O1b,
                 float* __restrict__ lsum2, float* __restrict__ clo2,
                 float* __restrict__ chi2)
{
    __shared__ ushort_t Ks[64 * LDK];
    __shared__ ushort_t Vs[64 * LDK];
    __shared__ ushort_t QpsP[64 * LDQP];
    __shared__ float mk[64];

    const int tid = threadIdx.x;
    const int blk = blockIdx.x;
    const int bh  = blk >> 5;
    const int qb  = (blk >> 1) & 15;
    const int ks  = blk & 1;
    const int b   = bh >> 4;
    const int q0  = qb * 64;
    const size_t gq0 = (size_t)bh * L_SEQ + q0;
    const int wave = tid >> 6, lane = tid & 63;
    const int lr = lane & 15, lq = lane >> 4;
    const int qw = wave * 16;

    const int sr0 = tid >> 3,          sc0 = (tid & 7) * 8;
    const int sr1 = (256 + tid) >> 3,  sc1 = ((256 + tid) & 7) * 8;
    const int qpRowL = qw + (lane >> 2);
    const int qpCol0 = (lane & 3) * 16;

    const ushort_t* Kg  = Ku  + (size_t)bh * (L_SEQ * DH);
    const ushort_t* Vtg = Vtu + (size_t)bh * (DH * L_SEQ);

    bf16x8 qa[2];
    {
        const ushort_t* qrow = Qu + (gq0 + qw + lr) * DH;
        #pragma unroll
        for (int kc = 0; kc < 2; kc++)
            qa[kc] = *(const bf16x8*)(qrow + kc * 32 + lq * 8);
    }

    if (ks == 0 && tid < 64) {
        const int q = q0 + tid;
        ushort_t* bandRow = SbandU + (gq0 + tid) * 256;
        for (int j = 0; j < 127 - q; j++)    bandRow[j] = 0;
        for (int j = 254; j > 1150 - q; j--) bandRow[j] = 0;
        bandRow[255] = 0;
    }

    f32x4 Oacc[4];
    #pragma unroll
    for (int j = 0; j < 4; j++) Oacc[j] = (f32x4){0.f, 0.f, 0.f, 0.f};
    float lpart[4] = {}, clpart[4] = {}, chpart[4] = {};

    uint4 kva0, kva1, kvb0, kvb1;
    ushort_t qpr[16];
    float mkr = 0.f;
    {
        const int k0 = ks * 512;
        kva0 = *(const uint4*)(Kg + (size_t)(k0 + sr0) * DH + sc0);
        kva1 = *(const uint4*)(Kg + (size_t)(k0 + sr1) * DH + sc1);
        kvb0 = *(const uint4*)(Vtg + (size_t)sr0 * L_SEQ + k0 + sc0);
        kvb1 = *(const uint4*)(Vtg + (size_t)sr1 * L_SEQ + k0 + sc1);
        const int qg = q0 + qpRowL;
        #pragma unroll
        for (int c = 0; c < 16; c++) {
            int rel = k0 + qpCol0 + c - qg;
            rel = rel < -128 ? -128 : (rel > 128 ? 128 : rel);
            qpr[c] = Qpu[(gq0 + qpRowL) * QP_STRIDE + rel + 128];
        }
        if (tid < 64) mkr = pm[b * L_SEQ + k0 + tid];
    }

    for (int t = 0; t < 8; t++) {
        const int k0 = (ks * 8 + t) * 64;
        __syncthreads();   // (a)

        *(uint4*)&Ks[sr0 * LDK + sc0] = kva0;
        *(uint4*)&Ks[sr1 * LDK + sc1] = kva1;
        *(uint4*)&Vs[sr0 * LDK + sc0] = kvb0;
        *(uint4*)&Vs[sr1 * LDK + sc1] = kvb1;
        {
            ushort_t* dst = &QpsP[qpRowL * LDQP + qpCol0];
            #pragma unroll
            for (int c = 0; c < 8; c++)
                ((unsigned*)dst)[c] = (unsigned)qpr[2*c] | ((unsigned)qpr[2*c+1] << 16);
        }
        if (tid < 64) mk[tid] = mkr;
        __syncthreads();   // (b)

        if (t < 7) {
            const int k0n = k0 + 64;
            kva0 = *(const uint4*)(Kg + (size_t)(k0n + sr0) * DH + sc0);
            kva1 = *(const uint4*)(Kg + (size_t)(k0n + sr1) * DH + sc1);
            kvb0 = *(const uint4*)(Vtg + (size_t)sr0 * L_SEQ + k0n + sc0);
            kvb1 = *(const uint4*)(Vtg + (size_t)sr1 * L_SEQ + k0n + sc1);
            const int qg = q0 + qpRowL;
            #pragma unroll
            for (int c = 0; c < 16; c++) {
                int rel = k0n + qpCol0 + c - qg;
                rel = rel < -128 ? -128 : (rel > 128 ? 128 : rel);
                qpr[c] = Qpu[(gq0 + qpRowL) * QP_STRIDE + rel + 128];
            }
            if (tid < 64) mkr = pm[b * L_SEQ + k0n + tid];
        }

        f32x4 Sacc[4];
        #pragma unroll
        for (int j = 0; j < 4; j++) Sacc[j] = (f32x4){0.f, 0.f, 0.f, 0.f};
        #pragma unroll
        for (int kc = 0; kc < 2; kc++) {
            #pragma unroll
            for (int j = 0; j < 4; j++) {
                bf16x8 kb = *(const bf16x8*)&Ks[(j*16 + lr) * LDK + kc*32 + lq*8];
                Sacc[j] = __builtin_amdgcn_mfma_f32_16x16x32_bf16(qa[kc], kb, Sacc[j], 0, 0, 0);
            }
        }

        ushort_t pb[4][4];
        #pragma unroll
        for (int r = 0; r < 4; r++) {
            const int ql = qw + lq*4 + r;
            const int q  = q0 + ql;
            const size_t gq = gq0 + ql;
            ushort_t* bandRow = SbandU + gq * 256 + 127;
            #pragma unroll
            for (int j = 0; j < 4; j++) {
                const int kl = j*16 + lr;
                const int k  = k0 + kl;
                const int rel = k - q;
                float s = (Sacc[j][r] + bf2f(QpsP[ql * LDQP + kl])) * 0.125f;
                s *= mk[kl];
                const float p = __expf(s);
                lpart[r] += p;
                const ushort_t ph = f2bf_rne(p);
                if (rel <= -128)      clpart[r] += p;
                else if (rel >= 128)  chpart[r] += p;
                else                  bandRow[rel] = ph;
                pb[j][r] = ph;
            }
        }

        #pragma unroll
        for (int r = 0; r < 4; r++)
            #pragma unroll
            for (int j = 0; j < 4; j++)
                QpsP[(qw + lq*4 + r) * LDQP + j*16 + lr] = pb[j][r];

        #pragma unroll
        for (int kc = 0; kc < 2; kc++) {
            bf16x8 pa = *(const bf16x8*)&QpsP[(qw + lr) * LDQP + kc*32 + lq*8];
            #pragma unroll
            for (int j = 0; j < 4; j++) {
                bf16x8 vb = *(const bf16x8*)&Vs[(j*16 + lr) * LDK + kc*32 + lq*8];
                Oacc[j] = __builtin_amdgcn_mfma_f32_16x16x32_bf16(pa, vb, Oacc[j], 0, 0, 0);
            }
        }
    }

    #pragma unroll
    for (int off = 1; off < 16; off <<= 1) {
        #pragma unroll
        for (int r = 0; r < 4; r++) {
            lpart[r]  += __shfl_xor(lpart[r],  off, 64);
            clpart[r] += __shfl_xor(clpart[r], off, 64);
            chpart[r] += __shfl_xor(chpart[r], off, 64);
        }
    }
    if (lr == 0) {
        #pragma unroll
        for (int r = 0; r < 4; r++) {
            const size_t o = (size_t)ks * GQ_TOT + gq0 + qw + lq*4 + r;
            lsum2[o] = lpart[r];
            clo2[o]  = clpart[r];
            chi2[o]  = chpart[r];
        }
    }

    ushort_t* O1o = ks ? O1b : O1a;
    #pragma unroll
    for (int j = 0; j < 4; j++)
        #pragma unroll
        for (int r = 0; r < 4; r++)
            O1o[(gq0 + qw + lq*4 + r) * DH + j*16 + lr] = f2bf_rne(Oacc[j][r]);
}

// ---------------------------------------------------------------------------
// post_mfma: O2 = band @ posV^T via MFMA; O1 partials now bf16.
// ---------------------------------------------------------------------------
__global__ __launch_bounds__(256)
void post_mfma(const ushort_t* __restrict__ SbandU, const ushort_t* __restrict__ pvTg,
               const ushort_t* __restrict__ O1a, const ushort_t* __restrict__ O1b,
               const float* __restrict__ lsum2, const float* __restrict__ clo2,
               const float* __restrict__ chi2, const float* __restrict__ posV,
               ushort_t* __restrict__ athi, ushort_t* __restrict__ atlo)
{
    __shared__ ushort_t pvT[64 * LDPV];
    const int tid = threadIdx.x;
    const size_t q0 = (size_t)blockIdx.x * 64;
    const int wave = tid >> 6, lane = tid & 63;
    const int w0 = wave >> 1, w1 = wave & 1;
    const int lr = lane & 15, lq = lane >> 4;

    {
        const unsigned* src = (const unsigned*)pvTg;
        unsigned* dst = (unsigned*)pvT;
        for (int i = tid; i < 64 * LDPV / 2; i += 256) dst[i] = src[i];
    }
    __syncthreads();

    f32x4 acc[2][2];
    #pragma unroll
    for (int i = 0; i < 2; i++)
        #pragma unroll
        for (int j = 0; j < 2; j++)
            acc[i][j] = (f32x4){0.f, 0.f, 0.f, 0.f};

    const ushort_t* bandB = SbandU + q0 * 256;
    #pragma unroll
    for (int kc = 0; kc < 8; kc++) {
        bf16x8 a[2], bv[2];
        #pragma unroll
        for (int i = 0; i < 2; i++) {
            a[i]  = *(const bf16x8*)&bandB[(size_t)(w0*32 + i*16 + lr) * 256 + kc*32 + lq*8];
            bv[i] = *(const bf16x8*)&pvT[(w1*32 + i*16 + lr) * LDPV + kc*32 + lq*8];
        }
        #pragma unroll
        for (int i = 0; i < 2; i++)
            #pragma unroll
            for (int j = 0; j < 2; j++)
                acc[i][j] = __builtin_amdgcn_mfma_f32_16x16x32_bf16(a[i], bv[j], acc[i][j], 0, 0, 0);
    }

    #pragma unroll
    for (int i = 0; i < 2; i++) {
        #pragma unroll
        for (int r = 0; r < 4; r++) {
            const int ql = w0*32 + i*16 + lq*4 + r;
            const size_t gq = q0 + ql;
            const float li = lsum2[gq] + lsum2[GQ_TOT + gq];
            const float cl = clo2[gq]  + clo2[GQ_TOT + gq];
            const float ch = chi2[gq]  + chi2[GQ_TOT + gq];
            const float inv = 1.0f / li;
            const int b  = (int)(gq >> 14);
            const int h  = (int)((gq >> 10) & 15);
            const int lp = (int)(gq & 1023);
            const size_t obase = ((size_t)(b * L_SEQ + lp) * 1024) + h * 64;
            #pragma unroll
            for (int j = 0; j < 2; j++) {
                const int dd = w1*32 + j*16 + lr;
                float o = bf2f(O1a[gq * DH + dd]) + bf2f(O1b[gq * DH + dd])
                        + acc[i][j][r]
                        + cl * posV[dd] + ch * posV[256 * 64 + dd];
                o *= inv;
                const ushort_t hh = f2bf_rne(o);
                const ushort_t ll = f2bf_rne(o - bf2f(hh));
                athi[obase + dd] = hh;
                atlo[obase + dd] = ll;
            }
        }
    }
}

// ---------------------------------------------------------------------------
extern "C" void kernel_launch(void* const* d_in, const int* in_sizes, int n_in,
                              void* d_out, int out_size, void* d_ws, size_t ws_size,
                              hipStream_t stream)
{
    const float* x    = (const float*)d_in[0];
    const float* pmk  = (const float*)d_in[1];
    const float* Wq   = (const float*)d_in[2];
    const float* bq   = (const float*)d_in[3];
    const float* Wk   = (const float*)d_in[4];
    const float* bk   = (const float*)d_in[5];
    const float* Wv   = (const float*)d_in[6];
    const float* bv   = (const float*)d_in[7];
    const float* Wo   = (const float*)d_in[8];
    const float* bo   = (const float*)d_in[9];
    const float* posK = (const float*)d_in[10];
    const float* posV = (const float*)d_in[11];
    float* out = (float*)d_out;

    // workspace carve-up (u16 first, then f32)
    ushort_t* u = (ushort_t*)d_ws;
    ushort_t* Qbu    = u;                                 // GQ*64 u16
    ushort_t* Kbu    = Qbu + (size_t)GQ_TOT * DH;
    ushort_t* Vtu    = Kbu + (size_t)GQ_TOT * DH;         // V^T
    ushort_t* Qpu    = Vtu + (size_t)GQ_TOT * DH;         // GQ*260
    ushort_t* SbandU = Qpu + (size_t)GQ_TOT * QP_STRIDE;  // GQ*256
    ushort_t* athi   = SbandU + (size_t)GQ_TOT * 256;
    ushort_t* atlo   = athi + (size_t)GQ_TOT * DH;
    ushort_t* O1a    = atlo + (size_t)GQ_TOT * DH;        // bf16 partials
    ushort_t* O1b    = O1a  + (size_t)GQ_TOT * DH;
    ushort_t* pvTg   = O1b  + (size_t)GQ_TOT * DH;
    float* lsum2 = (float*)(pvTg + 64 * LDPV + 64);       // 4B-aligned
    float* clo2  = lsum2 + 2 * (size_t)GQ_TOT;
    float* chi2  = clo2  + 2 * (size_t)GQ_TOT;

    // bf16 scratch aliased into the Sband region (disjoint lifetimes):
    // phase A (xhi 4.19M + wqkv hi/lo 6.29M = 10.5M u16 <= 16.78M region)
    // phase B (Wo hi/lo after post reads bands: 2.1M)
    ushort_t* bb    = SbandU;
    ushort_t* xhi   = bb;
    ushort_t* wqkvh = xhi + 4194304;       // [3072][1024]
    ushort_t* wqkvl = wqkvh + 3145728;
    ushort_t* woh   = bb;
    ushort_t* wol   = woh + 1048576;

    dim3 gb(256);

    split_f32_hi<<<dim3(2048), gb, 0, stream>>>(x, xhi);
    split_transpose3<<<dim3(16, 16, 3), gb, 0, stream>>>(Wq, Wk, Wv, wqkvh, wqkvl);
    prep_pvt<<<dim3(4), gb, 0, stream>>>(posV, pvTg);
    gemm_qkv128<<<dim3(32, 24), gb, 0, stream>>>(xhi, wqkvh, wqkvl, bq, bk, bv,
                                                 Qbu, Kbu, Vtu);
    qp_mfma<<<dim3(1024, 5), gb, 0, stream>>>(Qbu, posK, Qpu);
    attn_kernel<<<dim3(2048), gb, 0, stream>>>(Qbu, Kbu, Vtu, Qpu, pmk,
                                               SbandU, O1a, O1b, lsum2, clo2, chi2);
    post_mfma<<<dim3(GQ_TOT / 64), gb, 0, stream>>>(SbandU, pvTg, O1a, O1b, lsum2,
                                                    clo2, chi2, posV, athi, atlo);
    split_transpose<<<dim3(16, 16), gb, 0, stream>>>(Wo, woh, wol, 1024, 1024);
    gemm_mfma<<<dim3(64, 16), gb, 0, stream>>>(athi, atlo, woh, wol, bo, out,
                                               4096, 1024, 1024);
}